// Round 9
// baseline (2096.669 us; speedup 1.0000x reference)
//
#include <hip/hip_runtime.h>
#include <hip/hip_bf16.h>
#include <stdint.h>

#define M_DIM 8192
#define N_DIM 4096
#define K_DIM 4096
#define R_DIM 32
#define NT2   32     // K-tiles of 128 (= 2 quant groups of 64)
#define QMAXF 7.0f

using bf16_t = __hip_bfloat16;
typedef __attribute__((ext_vector_type(4)))  float f32x4;
typedef __attribute__((ext_vector_type(16))) float f32x16;
typedef __attribute__((ext_vector_type(8)))  short bf16x8;
typedef __attribute__((ext_vector_type(4)))  int   i32x4;
typedef __attribute__((ext_vector_type(16))) int   i32x16;

// ---------------------------------------------------------------------------
// async global->LDS stages (LDS dest = wave-uniform base + lane*size)
// ---------------------------------------------------------------------------
__device__ __forceinline__ void stage16(const void* g, void* l) {
  __builtin_amdgcn_global_load_lds(
      (const __attribute__((address_space(1))) unsigned int*)g,
      (__attribute__((address_space(3))) unsigned int*)l, 16, 0, 0);
}
__device__ __forceinline__ void stage4(const void* g, void* l) {
  __builtin_amdgcn_global_load_lds(
      (const __attribute__((address_space(1))) unsigned int*)g,
      (__attribute__((address_space(3))) unsigned int*)l, 4, 0, 0);
}

// ---------------------------------------------------------------------------
// prep kernel: block-range dispatch.
//   [0, 8192)      : quant_x  -> Aq int8 [8192][4096], sxT f32 [64][8192]
//   [8192, 12288)  : quant_w  -> Bq int8 [4096][4096], swT f32 [64][4096],
//                    luB bf16 [4096][32]
//   [12288, 12304) : ldT  (lora_down [K][R] -> bf16 ldT [R][K])
// ---------------------------------------------------------------------------
__global__ __launch_bounds__(256) void prep_kernel(
    const float* __restrict__ x, const float* __restrict__ smooth,
    const float* __restrict__ w, const float* __restrict__ lora_up,
    const float* __restrict__ ld,
    signed char* __restrict__ Aq, signed char* __restrict__ Bq,
    float* __restrict__ sxT, float* __restrict__ swT,
    bf16_t* __restrict__ luB, bf16_t* __restrict__ ldT) {
  const int bid = blockIdx.x;
  const int tid = threadIdx.x;

  if (bid < M_DIM) {                       // ---- quant_x ----
    const int row = bid;
    const int k0  = tid * 16;
    const float* xr = x + (size_t)row * K_DIM + k0;
    const float* sr = smooth + k0;

    float v[16];
#pragma unroll
    for (int i = 0; i < 4; ++i) {
      float4 xv = *(const float4*)(xr + i * 4);
      float4 sv = *(const float4*)(sr + i * 4);
      v[i*4+0] = xv.x * sv.x; v[i*4+1] = xv.y * sv.y;
      v[i*4+2] = xv.z * sv.z; v[i*4+3] = xv.w * sv.w;
    }
    float am = 0.f;
#pragma unroll
    for (int i = 0; i < 16; ++i) am = fmaxf(am, fabsf(v[i]));
    am = fmaxf(am, __shfl_xor(am, 1));
    am = fmaxf(am, __shfl_xor(am, 2));
    const float scale = fmaxf(am / QMAXF, 1e-8f);

    alignas(16) signed char o[16];
#pragma unroll
    for (int i = 0; i < 16; ++i) {
      float q = rintf(v[i] / scale);       // IEEE div + round-half-even = jnp
      q = fminf(fmaxf(q, -8.f), 7.f);
      o[i] = (signed char)(int)q;
    }
    *(uint4*)(Aq + (size_t)row * K_DIM + k0) = *(const uint4*)o;
    if ((tid & 3) == 0) sxT[(size_t)(tid >> 2) * M_DIM + row] = scale;

  } else if (bid < M_DIM + N_DIM) {        // ---- quant_w ----
    const int row = bid - M_DIM;
    const int k0  = tid * 16;
    const float* wr = w + (size_t)row * K_DIM + k0;

    float v[16];
#pragma unroll
    for (int i = 0; i < 4; ++i) {
      float4 wv = *(const float4*)(wr + i * 4);
      v[i*4+0] = wv.x; v[i*4+1] = wv.y; v[i*4+2] = wv.z; v[i*4+3] = wv.w;
    }
    float am = 0.f;
#pragma unroll
    for (int i = 0; i < 16; ++i) am = fmaxf(am, fabsf(v[i]));
    am = fmaxf(am, __shfl_xor(am, 1));
    am = fmaxf(am, __shfl_xor(am, 2));
    const float scale = fmaxf(am / QMAXF, 1e-8f);

    alignas(16) signed char o[16];
#pragma unroll
    for (int i = 0; i < 16; ++i) {
      float q = rintf(v[i] / scale);
      q = fminf(fmaxf(q, -8.f), 7.f);
      o[i] = (signed char)(int)q;
    }
    *(uint4*)(Bq + (size_t)row * K_DIM + k0) = *(const uint4*)o;
    if ((tid & 3) == 0) swT[(size_t)(tid >> 2) * N_DIM + row] = scale;
    if (tid < 32)
      luB[(size_t)row * R_DIM + tid] = __float2bfloat16(lora_up[row * R_DIM + tid]);

  } else {                                 // ---- ldT ----
    const int k = (bid - M_DIM - N_DIM) * 256 + tid;
    float v[R_DIM];
#pragma unroll
    for (int i = 0; i < R_DIM / 4; ++i) {
      float4 a = *(const float4*)(ld + (size_t)k * R_DIM + i * 4);
      v[i*4+0] = a.x; v[i*4+1] = a.y; v[i*4+2] = a.z; v[i*4+3] = a.w;
    }
#pragma unroll
    for (int r = 0; r < R_DIM; ++r)
      ldT[(size_t)r * K_DIM + k] = __float2bfloat16(v[r]);
  }
}

// ---------------------------------------------------------------------------
// t = (x*smooth) @ lora_down  [M x 32] via MFMA -> tB [8192][32] bf16.
// ---------------------------------------------------------------------------
__global__ __launch_bounds__(256) void lora_mfma_kernel(
    const float* __restrict__ x, const float* __restrict__ smooth,
    const bf16_t* __restrict__ ldT, bf16_t* __restrict__ tB) {
  const int tid  = threadIdx.x;
  const int w    = tid >> 6;
  const int lane = tid & 63;
  const int m0   = blockIdx.x * 32;

  const int mrow = m0 + (w >> 1) * 16 + (lane & 15);
  const int ncol = (w & 1) * 16 + (lane & 15);
  const float* xr = x + (size_t)mrow * K_DIM;
  const bf16_t* br = ldT + (size_t)ncol * K_DIM;

  f32x4 acc = {0.f, 0.f, 0.f, 0.f};
  union { bf16_t h[8]; bf16x8 v; } au;

  for (int k = 0; k < K_DIM; k += 32) {
    const int kf = k + (lane >> 4) * 8;
    float4 x0 = *(const float4*)(xr + kf);
    float4 x1 = *(const float4*)(xr + kf + 4);
    float4 s0 = *(const float4*)(smooth + kf);
    float4 s1 = *(const float4*)(smooth + kf + 4);
    au.h[0] = __float2bfloat16(x0.x * s0.x);
    au.h[1] = __float2bfloat16(x0.y * s0.y);
    au.h[2] = __float2bfloat16(x0.z * s0.z);
    au.h[3] = __float2bfloat16(x0.w * s0.w);
    au.h[4] = __float2bfloat16(x1.x * s1.x);
    au.h[5] = __float2bfloat16(x1.y * s1.y);
    au.h[6] = __float2bfloat16(x1.z * s1.z);
    au.h[7] = __float2bfloat16(x1.w * s1.w);
    bf16x8 bv = *(const bf16x8*)(br + kf);
    acc = __builtin_amdgcn_mfma_f32_16x16x32_bf16(au.v, bv, acc, 0, 0, 0);
  }

  const int orow = m0 + (w >> 1) * 16 + (lane >> 4) * 4;
#pragma unroll
  for (int q = 0; q < 4; ++q)
    tB[(size_t)(orow + q) * R_DIM + ncol] = __float2bfloat16(acc[q]);
}

// ---------------------------------------------------------------------------
// 256x256 int8 GEMM, BK=128 (2 groups/ktile), mfma_i32_32x32x32_i8.
// acc_f32 += sx_g[row]*sw_g[col]*int_dot per group; LoRA added as a bf16
// MFMA epilogue pass; bias fused in C write.
// Schedule: ONE interval per ktile, distance-1 ring, slot-disjoint:
//   [bar] read g0(cur); stage ktile u+1 -> buf cur^1 (never read here);
//   MFMA+scale g0; read g1(cur); MFMA+scale g1; vmcnt(0); bar.
// Overwrites of buf cur happen only next interval (all reads of cur were
// consumed before this interval's end barrier).  LDS tile geometry is
// byte-identical to the round-7 bf16 tile (256 rows x 128B, 8x16B granules,
// key(row)=(row^(row>>3))&7) -> measured-0-conflict swizzle transfers.
// LDS: A 2x32K | B 2x32K | sx 2x2K | sw 2x2K = 136 KiB dynamic.
// ---------------------------------------------------------------------------
__global__ __launch_bounds__(512, 2) void gemm_i8_kernel(
    const signed char* __restrict__ Aq, const signed char* __restrict__ Bq,
    const float* __restrict__ sxT, const float* __restrict__ swT,
    const bf16_t* __restrict__ tB, const bf16_t* __restrict__ luB,
    const float* __restrict__ bias, float* __restrict__ C) {
  extern __shared__ __align__(16) char lds[];   // 139264 B

  // XCD-aware swizzle: nwg = 512, divisible by 8
  const int wg  = blockIdx.x;
  const int swz = (wg & 7) * 64 + (wg >> 3);
  const int bn  = swz & 15;    // 0..15
  const int bm  = swz >> 4;    // 0..31

  const int tid  = threadIdx.x;
  const int lane = tid & 63;
  const int wid  = tid >> 6;     // 0..7
  const int wm   = wid >> 2;     // 0..1
  const int wn   = wid & 3;      // 0..3

  const int l31 = lane & 31;
  const int lh  = lane >> 5;
  const int l7  = lane & 7;
  const int rk  = l31 >> 3;

  // staging: thread (sr,sl); source col granule = sl ^ key(sr); dest linear
  const int sr    = tid >> 3;                 // 0..63
  const int sl    = tid & 7;
  const int gbyte = (sl ^ ((sr ^ (sr >> 3)) & 7)) << 4;
  const signed char* Abase = Aq + (size_t)(bm * 256 + sr) * K_DIM + gbyte;
  const signed char* Bbase = Bq + (size_t)(bn * 256 + sr) * K_DIM + gbyte;

  char* ldsA  = lds;               // [2][32768]
  char* ldsB  = lds + 65536;       // [2][32768]
  char* ldsSX = lds + 131072;      // [2][2048]  f32 [2 groups][256 rows]
  char* ldsSW = lds + 135168;      // [2][2048]

#define STAGE_ALL(buf, u) do {                                                 \
    _Pragma("unroll")                                                          \
    for (int j = 0; j < 4; ++j) {                                              \
      stage16(Abase + (size_t)(64 * j) * K_DIM + (u) * 128,                    \
              ldsA + (buf) * 32768 + j * 8192 + tid * 16);                     \
      stage16(Bbase + (size_t)(64 * j) * K_DIM + (u) * 128,                    \
              ldsB + (buf) * 32768 + j * 8192 + tid * 16);                     \
    }                                                                          \
    stage4(sxT + (size_t)(2 * (u) + (tid >> 8)) * M_DIM + bm * 256 + (tid & 255), \
           ldsSX + (buf) * 2048 + tid * 4);                                    \
    stage4(swT + (size_t)(2 * (u) + (tid >> 8)) * N_DIM + bn * 256 + (tid & 255), \
           ldsSW + (buf) * 2048 + tid * 4);                                    \
  } while (0)

  f32x16 acc[8] = {};   // [rt*2 + ct]
  i32x4  aF[4][2];      // [rt][kt]
  i32x4  bF[2][2];      // [ct][kt]
  float  swv[2];

  // read group g0 operands + col scales from buf cb
#define READ_G(g0, cb) do {                                                    \
    _Pragma("unroll")                                                          \
    for (int rt = 0; rt < 4; ++rt) {                                           \
      const char* pa_ = ldsA + (cb) * 32768 + (wm * 128 + rt * 32 + l31) * 128;\
      _Pragma("unroll")                                                        \
      for (int kt = 0; kt < 2; ++kt)                                           \
        aF[rt][kt] = *(const i32x4*)(pa_ +                                     \
          ((((g0) * 4 + kt * 2 + lh) ^ l7 ^ ((rt * 4 + rk) & 7)) << 4));       \
    }                                                                          \
    _Pragma("unroll")                                                          \
    for (int ct = 0; ct < 2; ++ct) {                                           \
      const char* pb_ = ldsB + (cb) * 32768 + (wn * 64 + ct * 32 + l31) * 128; \
      _Pragma("unroll")                                                        \
      for (int kt = 0; kt < 2; ++kt)                                           \
        bF[ct][kt] = *(const i32x4*)(pb_ +                                     \
          ((((g0) * 4 + kt * 2 + lh) ^ l7 ^ ((ct * 4 + rk) & 7)) << 4));       \
      swv[ct] = *(const float*)(ldsSW + (cb) * 2048 + (g0) * 1024 +            \
                                (wn * 64 + ct * 32 + l31) * 4);                \
    }                                                                          \
  } while (0)

  // MFMA + per-group scale application for group g0 of buf cb
#define COMPUTE_G(g0, cb) do {                                                 \
    const float* sxp_ = (const float*)(ldsSX + (cb) * 2048 + (g0) * 1024) +    \
                        wm * 128 + lh * 4;                                     \
    _Pragma("unroll")                                                          \
    for (int rt = 0; rt < 4; ++rt)                                             \
      _Pragma("unroll")                                                        \
      for (int ct = 0; ct < 2; ++ct) {                                         \
        i32x16 ai = {};                                                        \
        ai = __builtin_amdgcn_mfma_i32_32x32x32_i8(aF[rt][0], bF[ct][0], ai, 0, 0, 0); \
        ai = __builtin_amdgcn_mfma_i32_32x32x32_i8(aF[rt][1], bF[ct][1], ai, 0, 0, 0); \
        _Pragma("unroll")                                                      \
        for (int q = 0; q < 4; ++q) {                                          \
          f32x4 sx4 = *(const f32x4*)(sxp_ + rt * 32 + q * 8);                 \
          _Pragma("unroll")                                                    \
          for (int j = 0; j < 4; ++j)                                          \
            acc[rt * 2 + ct][q * 4 + j] +=                                     \
                sx4[j] * swv[ct] * (float)ai[q * 4 + j];                       \
        }                                                                      \
      }                                                                        \
  } while (0)

  // ---- prologue: stage ktile0 into buf0; drain; enter loop ----
  STAGE_ALL(0, 0);
  asm volatile("s_waitcnt vmcnt(0)" ::: "memory");
  __builtin_amdgcn_s_barrier();

  for (int u = 0; u < NT2; ++u) {
    const int cur = u & 1;
    READ_G(0, cur);
    if (u + 1 < NT2) STAGE_ALL(cur ^ 1, u + 1);   // other buffer: slot-disjoint
    asm volatile("s_waitcnt lgkmcnt(0)" ::: "memory");
    __builtin_amdgcn_s_setprio(1);
    COMPUTE_G(0, cur);
    __builtin_amdgcn_s_setprio(0);
    READ_G(1, cur);
    asm volatile("s_waitcnt lgkmcnt(0)" ::: "memory");
    __builtin_amdgcn_s_setprio(1);
    COMPUTE_G(1, cur);
    __builtin_amdgcn_s_setprio(0);
    asm volatile("s_waitcnt vmcnt(0)" ::: "memory");  // next ktile staged
    __builtin_amdgcn_s_barrier();
  }

  // ---- LoRA epilogue: acc += t_tile @ lu_tile^T (bf16 MFMA, K=32) ----
  stage16(tB  + (size_t)bm * 8192 + tid * 8,        ldsA + tid * 16);
  stage16(tB  + (size_t)bm * 8192 + 4096 + tid * 8, ldsA + 8192 + tid * 16);
  stage16(luB + (size_t)bn * 8192 + tid * 8,        ldsB + tid * 16);
  stage16(luB + (size_t)bn * 8192 + 4096 + tid * 8, ldsB + 8192 + tid * 16);
  asm volatile("s_waitcnt vmcnt(0)" ::: "memory");
  __builtin_amdgcn_s_barrier();
  {
    bf16x8 tf[4][2], lf[2][2];
#pragma unroll
    for (int rt = 0; rt < 4; ++rt) {
      const char* pt = ldsA + (wm * 128 + rt * 32 + l31) * 64 + lh * 16;
      tf[rt][0] = *(const bf16x8*)(pt);
      tf[rt][1] = *(const bf16x8*)(pt + 32);
    }
#pragma unroll
    for (int ct = 0; ct < 2; ++ct) {
      const char* pl = ldsB + (wn * 64 + ct * 32 + l31) * 64 + lh * 16;
      lf[ct][0] = *(const bf16x8*)(pl);
      lf[ct][1] = *(const bf16x8*)(pl + 32);
    }
    asm volatile("s_waitcnt lgkmcnt(0)" ::: "memory");
#pragma unroll
    for (int s = 0; s < 2; ++s)
#pragma unroll
      for (int rt = 0; rt < 4; ++rt)
#pragma unroll
        for (int ct = 0; ct < 2; ++ct)
          acc[rt * 2 + ct] = __builtin_amdgcn_mfma_f32_32x32x16_bf16(
              tf[rt][s], lf[ct][s], acc[rt * 2 + ct], 0, 0, 0);
  }

  // ---- C write: 32x32 C/D: col=lane&31, row=(e&3)+8*(e>>2)+4*lh ----
#pragma unroll
  for (int rt = 0; rt < 4; ++rt) {
#pragma unroll
    for (int ct = 0; ct < 2; ++ct) {
      const int gc = bn * 256 + wn * 64 + ct * 32 + l31;
      const float bv = bias[gc];
      const int gr0 = bm * 256 + wm * 128 + rt * 32 + lh * 4;
#pragma unroll
      for (int e = 0; e < 16; ++e) {
        const int gr = gr0 + (e & 3) + 8 * (e >> 2);
        C[(size_t)gr * N_DIM + gc] = acc[rt * 2 + ct][e] + bv;
      }
    }
  }
#undef STAGE_ALL
#undef READ_G
#undef COMPUTE_G
}

// ---------------------------------------------------------------------------
extern "C" void kernel_launch(void* const* d_in, const int* in_sizes, int n_in,
                              void* d_out, int out_size, void* d_ws, size_t ws_size,
                              hipStream_t stream) {
  const float* x         = (const float*)d_in[0];
  const float* w_res     = (const float*)d_in[1];
  const float* lora_down = (const float*)d_in[2];
  const float* lora_up   = (const float*)d_in[3];
  const float* smooth    = (const float*)d_in[4];
  const float* b         = (const float*)d_in[5];
  float* out = (float*)d_out;

  // workspace carve-up (54.5 MB total)
  signed char* Aq  = (signed char*)d_ws;                       // 32 MB
  signed char* Bq  = Aq + (size_t)M_DIM * K_DIM;               // 16 MB
  float*       sxT = (float*)(Bq + (size_t)N_DIM * K_DIM);     // 2 MB [64][8192]
  float*       swT = sxT + (size_t)64 * M_DIM;                 // 1 MB [64][4096]
  bf16_t*      ldT = (bf16_t*)(swT + (size_t)64 * N_DIM);      // 256 KB [32][4096]
  bf16_t*      tB  = ldT + (size_t)R_DIM * K_DIM;              // 512 KB [8192][32]
  bf16_t*      luB = tB + (size_t)M_DIM * R_DIM;               // 256 KB [4096][32]

  hipFuncSetAttribute((const void*)gemm_i8_kernel,
                      hipFuncAttributeMaxDynamicSharedMemorySize, 139264);

  prep_kernel<<<M_DIM + N_DIM + K_DIM / 256, 256, 0, stream>>>(
      x, smooth, w_res, lora_up, lora_down, Aq, Bq, sxT, swT, luB, ldT);
  lora_mfma_kernel<<<M_DIM / 32, 256, 0, stream>>>(x, smooth, ldT, tB);
  gemm_i8_kernel<<<(M_DIM / 256) * (N_DIM / 256), 512, 139264, stream>>>(
      Aq, Bq, sxT, swT, tB, luB, b, out);
}

// Round 10
// 421.202 us; speedup vs baseline: 4.9778x; 4.9778x over previous
//
#include <hip/hip_runtime.h>
#include <hip/hip_bf16.h>
#include <stdint.h>

#define M_DIM 8192
#define N_DIM 4096
#define K_DIM 4096
#define R_DIM 32
#define NT2   32     // K-tiles of 128 (= 2 quant groups of 64)
#define QMAXF 7.0f

using bf16_t = __hip_bfloat16;
typedef __attribute__((ext_vector_type(4)))  float f32x4;
typedef __attribute__((ext_vector_type(16))) float f32x16;
typedef __attribute__((ext_vector_type(8)))  short bf16x8;
typedef __attribute__((ext_vector_type(4)))  int   i32x4;
typedef __attribute__((ext_vector_type(16))) int   i32x16;

// ---------------------------------------------------------------------------
// async global->LDS stages (LDS dest = wave-uniform base + lane*size)
// ---------------------------------------------------------------------------
__device__ __forceinline__ void stage16(const void* g, void* l) {
  __builtin_amdgcn_global_load_lds(
      (const __attribute__((address_space(1))) unsigned int*)g,
      (__attribute__((address_space(3))) unsigned int*)l, 16, 0, 0);
}
__device__ __forceinline__ void stage4(const void* g, void* l) {
  __builtin_amdgcn_global_load_lds(
      (const __attribute__((address_space(1))) unsigned int*)g,
      (__attribute__((address_space(3))) unsigned int*)l, 4, 0, 0);
}

// ---------------------------------------------------------------------------
// prep kernel: block-range dispatch.
//   [0, 8192)      : quant_x  -> Aq int8 [8192][4096], sxT f32 [64][8192]
//   [8192, 12288)  : quant_w  -> Bq int8 [4096][4096], swT f32 [64][4096],
//                    luB bf16 [4096][32]
//   [12288, 12304) : ldT  (lora_down [K][R] -> bf16 ldT [R][K])
// ---------------------------------------------------------------------------
__global__ __launch_bounds__(256) void prep_kernel(
    const float* __restrict__ x, const float* __restrict__ smooth,
    const float* __restrict__ w, const float* __restrict__ lora_up,
    const float* __restrict__ ld,
    signed char* __restrict__ Aq, signed char* __restrict__ Bq,
    float* __restrict__ sxT, float* __restrict__ swT,
    bf16_t* __restrict__ luB, bf16_t* __restrict__ ldT) {
  const int bid = blockIdx.x;
  const int tid = threadIdx.x;

  if (bid < M_DIM) {                       // ---- quant_x ----
    const int row = bid;
    const int k0  = tid * 16;
    const float* xr = x + (size_t)row * K_DIM + k0;
    const float* sr = smooth + k0;

    float v[16];
#pragma unroll
    for (int i = 0; i < 4; ++i) {
      float4 xv = *(const float4*)(xr + i * 4);
      float4 sv = *(const float4*)(sr + i * 4);
      v[i*4+0] = xv.x * sv.x; v[i*4+1] = xv.y * sv.y;
      v[i*4+2] = xv.z * sv.z; v[i*4+3] = xv.w * sv.w;
    }
    float am = 0.f;
#pragma unroll
    for (int i = 0; i < 16; ++i) am = fmaxf(am, fabsf(v[i]));
    am = fmaxf(am, __shfl_xor(am, 1));
    am = fmaxf(am, __shfl_xor(am, 2));
    const float scale = fmaxf(am / QMAXF, 1e-8f);

    alignas(16) signed char o[16];
#pragma unroll
    for (int i = 0; i < 16; ++i) {
      float q = rintf(v[i] / scale);       // IEEE div + round-half-even = jnp
      q = fminf(fmaxf(q, -8.f), 7.f);
      o[i] = (signed char)(int)q;
    }
    *(uint4*)(Aq + (size_t)row * K_DIM + k0) = *(const uint4*)o;
    if ((tid & 3) == 0) sxT[(size_t)(tid >> 2) * M_DIM + row] = scale;

  } else if (bid < M_DIM + N_DIM) {        // ---- quant_w ----
    const int row = bid - M_DIM;
    const int k0  = tid * 16;
    const float* wr = w + (size_t)row * K_DIM + k0;

    float v[16];
#pragma unroll
    for (int i = 0; i < 4; ++i) {
      float4 wv = *(const float4*)(wr + i * 4);
      v[i*4+0] = wv.x; v[i*4+1] = wv.y; v[i*4+2] = wv.z; v[i*4+3] = wv.w;
    }
    float am = 0.f;
#pragma unroll
    for (int i = 0; i < 16; ++i) am = fmaxf(am, fabsf(v[i]));
    am = fmaxf(am, __shfl_xor(am, 1));
    am = fmaxf(am, __shfl_xor(am, 2));
    const float scale = fmaxf(am / QMAXF, 1e-8f);

    alignas(16) signed char o[16];
#pragma unroll
    for (int i = 0; i < 16; ++i) {
      float q = rintf(v[i] / scale);
      q = fminf(fmaxf(q, -8.f), 7.f);
      o[i] = (signed char)(int)q;
    }
    *(uint4*)(Bq + (size_t)row * K_DIM + k0) = *(const uint4*)o;
    if ((tid & 3) == 0) swT[(size_t)(tid >> 2) * N_DIM + row] = scale;
    if (tid < 32)
      luB[(size_t)row * R_DIM + tid] = __float2bfloat16(lora_up[row * R_DIM + tid]);

  } else {                                 // ---- ldT ----
    const int k = (bid - M_DIM - N_DIM) * 256 + tid;
    float v[R_DIM];
#pragma unroll
    for (int i = 0; i < R_DIM / 4; ++i) {
      float4 a = *(const float4*)(ld + (size_t)k * R_DIM + i * 4);
      v[i*4+0] = a.x; v[i*4+1] = a.y; v[i*4+2] = a.z; v[i*4+3] = a.w;
    }
#pragma unroll
    for (int r = 0; r < R_DIM; ++r)
      ldT[(size_t)r * K_DIM + k] = __float2bfloat16(v[r]);
  }
}

// ---------------------------------------------------------------------------
// t = (x*smooth) @ lora_down  [M x 32] via MFMA -> tB [8192][32] bf16.
// ---------------------------------------------------------------------------
__global__ __launch_bounds__(256) void lora_mfma_kernel(
    const float* __restrict__ x, const float* __restrict__ smooth,
    const bf16_t* __restrict__ ldT, bf16_t* __restrict__ tB) {
  const int tid  = threadIdx.x;
  const int w    = tid >> 6;
  const int lane = tid & 63;
  const int m0   = blockIdx.x * 32;

  const int mrow = m0 + (w >> 1) * 16 + (lane & 15);
  const int ncol = (w & 1) * 16 + (lane & 15);
  const float* xr = x + (size_t)mrow * K_DIM;
  const bf16_t* br = ldT + (size_t)ncol * K_DIM;

  f32x4 acc = {0.f, 0.f, 0.f, 0.f};
  union { bf16_t h[8]; bf16x8 v; } au;

  for (int k = 0; k < K_DIM; k += 32) {
    const int kf = k + (lane >> 4) * 8;
    float4 x0 = *(const float4*)(xr + kf);
    float4 x1 = *(const float4*)(xr + kf + 4);
    float4 s0 = *(const float4*)(smooth + kf);
    float4 s1 = *(const float4*)(smooth + kf + 4);
    au.h[0] = __float2bfloat16(x0.x * s0.x);
    au.h[1] = __float2bfloat16(x0.y * s0.y);
    au.h[2] = __float2bfloat16(x0.z * s0.z);
    au.h[3] = __float2bfloat16(x0.w * s0.w);
    au.h[4] = __float2bfloat16(x1.x * s1.x);
    au.h[5] = __float2bfloat16(x1.y * s1.y);
    au.h[6] = __float2bfloat16(x1.z * s1.z);
    au.h[7] = __float2bfloat16(x1.w * s1.w);
    bf16x8 bv = *(const bf16x8*)(br + kf);
    acc = __builtin_amdgcn_mfma_f32_16x16x32_bf16(au.v, bv, acc, 0, 0, 0);
  }

  const int orow = m0 + (w >> 1) * 16 + (lane >> 4) * 4;
#pragma unroll
  for (int q = 0; q < 4; ++q)
    tB[(size_t)(orow + q) * R_DIM + ncol] = __float2bfloat16(acc[q]);
}

// ---------------------------------------------------------------------------
// 256x128 int8 GEMM, BK=128 (2 groups/ktile), mfma_i32_32x32x32_i8.
// 8 waves (4M x 2N); wave tile 64x64 = 2x2 of 32x32 -> acc = 4 x f32x16
// (64 VGPR -- fits, no spill; round 9's 128-VGPR acc spilled 8.4 GB).
// Schedule: round-9-proven one-interval slot-disjoint distance-1 ring.
// Swizzle: key(row)=(row^(row>>3))&7 both sides (round-7-measured 0 conflict;
// byte-identical 128B-row geometry).  Scales staged to LDS; sx4 reads are
// 2-address broadcasts, swv reads 32-consecutive-f32 (conflict-free).
// LoRA epilogue reads tB/luB fragments directly from global (L2-resident).
// LDS: A 2x32K | B 2x16K | sx 2x2K | sw 2x1K = 102 KiB dynamic.
// ---------------------------------------------------------------------------
__global__ __launch_bounds__(512, 2) void gemm_i8_kernel(
    const signed char* __restrict__ Aq, const signed char* __restrict__ Bq,
    const float* __restrict__ sxT, const float* __restrict__ swT,
    const bf16_t* __restrict__ tB, const bf16_t* __restrict__ luB,
    const float* __restrict__ bias, float* __restrict__ C) {
  extern __shared__ __align__(16) char lds[];   // 104448 B

  // XCD-aware swizzle: nwg = 1024, divisible by 8
  const int wg  = blockIdx.x;
  const int swz = (wg & 7) * 128 + (wg >> 3);
  const int bn  = swz & 31;    // 0..31 (128-col tiles)
  const int bm  = swz >> 5;    // 0..31 (256-row tiles)

  const int tid  = threadIdx.x;
  const int lane = tid & 63;
  const int wid  = tid >> 6;     // 0..7
  const int wm   = wid >> 1;     // 0..3
  const int wn   = wid & 1;      // 0..1

  const int l31 = lane & 31;
  const int lh  = lane >> 5;
  const int l7  = lane & 7;
  const int rk  = l31 >> 3;

  // staging: thread (sr,sl); source col granule = sl ^ key(sr); dest linear
  const int sr    = tid >> 3;                 // 0..63
  const int sl    = tid & 7;
  const int gbyte = (sl ^ ((sr ^ (sr >> 3)) & 7)) << 4;
  const signed char* Abase = Aq + (size_t)(bm * 256 + sr) * K_DIM + gbyte;
  const signed char* Bbase = Bq + (size_t)(bn * 128 + sr) * K_DIM + gbyte;

  char* ldsA  = lds;               // [2][32768]
  char* ldsB  = lds + 65536;       // [2][16384]
  char* ldsSX = lds + 98304;       // [2][2048]  f32 [2 groups][256 rows]
  char* ldsSW = lds + 102400;      // [2][1024]  f32 [2 groups][128 rows]

#define STAGE_ALL(buf, u) do {                                                 \
    _Pragma("unroll")                                                          \
    for (int j = 0; j < 4; ++j)                                                \
      stage16(Abase + (size_t)(64 * j) * K_DIM + (u) * 128,                    \
              ldsA + (buf) * 32768 + j * 8192 + tid * 16);                     \
    _Pragma("unroll")                                                          \
    for (int j = 0; j < 2; ++j)                                                \
      stage16(Bbase + (size_t)(64 * j) * K_DIM + (u) * 128,                    \
              ldsB + (buf) * 16384 + j * 8192 + tid * 16);                     \
    stage4(sxT + (size_t)(2 * (u) + (tid >> 8)) * M_DIM + bm * 256 + (tid & 255), \
           ldsSX + (buf) * 2048 + tid * 4);                                    \
    if (tid < 256)                                                             \
      stage4(swT + (size_t)(2 * (u) + (tid >> 7)) * N_DIM + bn * 128 + (tid & 127), \
             ldsSW + (buf) * 1024 + tid * 4);                                  \
  } while (0)

  f32x16 acc[4] = {};   // [rt*2 + ct]
  i32x4  aF[2][2];      // [rt][kt]
  i32x4  bF[2][2];      // [ct][kt]
  float  swv[2];

  // read group g operands + col scales from buf cb
#define READ_G(g, cb) do {                                                     \
    _Pragma("unroll")                                                          \
    for (int rt = 0; rt < 2; ++rt) {                                           \
      const char* pa_ = ldsA + (cb) * 32768 + (wm * 64 + rt * 32 + l31) * 128; \
      _Pragma("unroll")                                                        \
      for (int kt = 0; kt < 2; ++kt)                                           \
        aF[rt][kt] = *(const i32x4*)(pa_ +                                     \
          ((((g) * 4 + kt * 2 + lh) ^ l7 ^ ((rt * 4 + rk) & 7)) << 4));        \
    }                                                                          \
    _Pragma("unroll")                                                          \
    for (int ct = 0; ct < 2; ++ct) {                                           \
      const char* pb_ = ldsB + (cb) * 16384 + (wn * 64 + ct * 32 + l31) * 128; \
      _Pragma("unroll")                                                        \
      for (int kt = 0; kt < 2; ++kt)                                           \
        bF[ct][kt] = *(const i32x4*)(pb_ +                                     \
          ((((g) * 4 + kt * 2 + lh) ^ l7 ^ ((ct * 4 + rk) & 7)) << 4));        \
      swv[ct] = *(const float*)(ldsSW + (cb) * 1024 + (g) * 512 +              \
                                (wn * 64 + ct * 32 + l31) * 4);                \
    }                                                                          \
  } while (0)

  // MFMA + per-group scale application for group g of buf cb
#define COMPUTE_G(g, cb) do {                                                  \
    const float* sxp_ = (const float*)(ldsSX + (cb) * 2048 + (g) * 1024) +     \
                        wm * 64 + lh * 4;                                      \
    _Pragma("unroll")                                                          \
    for (int rt = 0; rt < 2; ++rt)                                             \
      _Pragma("unroll")                                                        \
      for (int ct = 0; ct < 2; ++ct) {                                         \
        i32x16 ai = {};                                                        \
        ai = __builtin_amdgcn_mfma_i32_32x32x32_i8(aF[rt][0], bF[ct][0], ai, 0, 0, 0); \
        ai = __builtin_amdgcn_mfma_i32_32x32x32_i8(aF[rt][1], bF[ct][1], ai, 0, 0, 0); \
        _Pragma("unroll")                                                      \
        for (int q = 0; q < 4; ++q) {                                          \
          f32x4 sx4 = *(const f32x4*)(sxp_ + rt * 32 + q * 8);                 \
          f32x4 p4 = sx4 * swv[ct];                                            \
          _Pragma("unroll")                                                    \
          for (int j = 0; j < 4; ++j)                                          \
            acc[rt * 2 + ct][q * 4 + j] += p4[j] * (float)ai[q * 4 + j];       \
        }                                                                      \
      }                                                                        \
  } while (0)

  // ---- prologue: stage ktile0 into buf0; drain; enter loop ----
  STAGE_ALL(0, 0);
  asm volatile("s_waitcnt vmcnt(0)" ::: "memory");
  __builtin_amdgcn_s_barrier();

  for (int u = 0; u < NT2; ++u) {
    const int cur = u & 1;
    READ_G(0, cur);
    if (u + 1 < NT2) STAGE_ALL(cur ^ 1, u + 1);   // other buffer: slot-disjoint
    asm volatile("s_waitcnt lgkmcnt(0)" ::: "memory");
    __builtin_amdgcn_s_setprio(1);
    COMPUTE_G(0, cur);
    __builtin_amdgcn_s_setprio(0);
    READ_G(1, cur);
    asm volatile("s_waitcnt lgkmcnt(0)" ::: "memory");
    __builtin_amdgcn_s_setprio(1);
    COMPUTE_G(1, cur);
    __builtin_amdgcn_s_setprio(0);
    asm volatile("s_waitcnt vmcnt(0)" ::: "memory");  // next ktile staged
    __builtin_amdgcn_s_barrier();
  }

  // ---- LoRA epilogue: acc += t_tile @ lu_tile^T (bf16 MFMA, K=32),
  //      fragments read directly from global (L2-resident, once/block) ----
  {
    bf16x8 tf[2][2], lf[2][2];   // [rt][s], [ct][s]
#pragma unroll
    for (int rt = 0; rt < 2; ++rt) {
      const bf16_t* pt = tB + (size_t)(bm * 256 + wm * 64 + rt * 32 + l31) * R_DIM + lh * 8;
      tf[rt][0] = *(const bf16x8*)(pt);
      tf[rt][1] = *(const bf16x8*)(pt + 16);
    }
#pragma unroll
    for (int ct = 0; ct < 2; ++ct) {
      const bf16_t* pl = luB + (size_t)(bn * 128 + wn * 64 + ct * 32 + l31) * R_DIM + lh * 8;
      lf[ct][0] = *(const bf16x8*)(pl);
      lf[ct][1] = *(const bf16x8*)(pl + 16);
    }
#pragma unroll
    for (int s = 0; s < 2; ++s)
#pragma unroll
      for (int rt = 0; rt < 2; ++rt)
#pragma unroll
        for (int ct = 0; ct < 2; ++ct)
          acc[rt * 2 + ct] = __builtin_amdgcn_mfma_f32_32x32x16_bf16(
              tf[rt][s], lf[ct][s], acc[rt * 2 + ct], 0, 0, 0);
  }

  // ---- C write: 32x32 C/D: col=lane&31, row=(e&3)+8*(e>>2)+4*lh ----
#pragma unroll
  for (int rt = 0; rt < 2; ++rt) {
#pragma unroll
    for (int ct = 0; ct < 2; ++ct) {
      const int gc = bn * 128 + wn * 64 + ct * 32 + l31;
      const float bv = bias[gc];
      const int gr0 = bm * 256 + wm * 64 + rt * 32 + lh * 4;
#pragma unroll
      for (int e = 0; e < 16; ++e) {
        const int gr = gr0 + (e & 3) + 8 * (e >> 2);
        C[(size_t)gr * N_DIM + gc] = acc[rt * 2 + ct][e] + bv;
      }
    }
  }
#undef STAGE_ALL
#undef READ_G
#undef COMPUTE_G
}

// ---------------------------------------------------------------------------
extern "C" void kernel_launch(void* const* d_in, const int* in_sizes, int n_in,
                              void* d_out, int out_size, void* d_ws, size_t ws_size,
                              hipStream_t stream) {
  const float* x         = (const float*)d_in[0];
  const float* w_res     = (const float*)d_in[1];
  const float* lora_down = (const float*)d_in[2];
  const float* lora_up   = (const float*)d_in[3];
  const float* smooth    = (const float*)d_in[4];
  const float* b         = (const float*)d_in[5];
  float* out = (float*)d_out;

  // workspace carve-up (54.5 MB total)
  signed char* Aq  = (signed char*)d_ws;                       // 32 MB
  signed char* Bq  = Aq + (size_t)M_DIM * K_DIM;               // 16 MB
  float*       sxT = (float*)(Bq + (size_t)N_DIM * K_DIM);     // 2 MB [64][8192]
  float*       swT = sxT + (size_t)64 * M_DIM;                 // 1 MB [64][4096]
  bf16_t*      ldT = (bf16_t*)(swT + (size_t)64 * N_DIM);      // 256 KB [32][4096]
  bf16_t*      tB  = ldT + (size_t)R_DIM * K_DIM;              // 512 KB [8192][32]
  bf16_t*      luB = tB + (size_t)M_DIM * R_DIM;               // 256 KB [4096][32]

  hipFuncSetAttribute((const void*)gemm_i8_kernel,
                      hipFuncAttributeMaxDynamicSharedMemorySize, 104448);

  prep_kernel<<<M_DIM + N_DIM + K_DIM / 256, 256, 0, stream>>>(
      x, smooth, w_res, lora_up, lora_down, Aq, Bq, sxT, swT, luB, ldT);
  lora_mfma_kernel<<<M_DIM / 32, 256, 0, stream>>>(x, smooth, ldT, tB);
  gemm_i8_kernel<<<(M_DIM / 256) * (N_DIM / 128), 512, 104448, stream>>>(
      Aq, Bq, sxT, swT, tB, luB, b, out);
}

// Round 11
// 419.801 us; speedup vs baseline: 4.9944x; 1.0033x over previous
//
#include <hip/hip_runtime.h>
#include <hip/hip_bf16.h>
#include <stdint.h>

#define M_DIM 8192
#define N_DIM 4096
#define K_DIM 4096
#define R_DIM 32
#define NT2   32     // K-tiles of 128 (= 2 quant groups of 64)
#define QMAXF 7.0f

using bf16_t = __hip_bfloat16;
typedef __attribute__((ext_vector_type(4)))  float f32x4;
typedef __attribute__((ext_vector_type(16))) float f32x16;
typedef __attribute__((ext_vector_type(8)))  short bf16x8;
typedef __attribute__((ext_vector_type(4)))  int   i32x4;
typedef __attribute__((ext_vector_type(16))) int   i32x16;

// ---------------------------------------------------------------------------
// async global->LDS stages (LDS dest = wave-uniform base + lane*size)
// ---------------------------------------------------------------------------
__device__ __forceinline__ void stage16(const void* g, void* l) {
  __builtin_amdgcn_global_load_lds(
      (const __attribute__((address_space(1))) unsigned int*)g,
      (__attribute__((address_space(3))) unsigned int*)l, 16, 0, 0);
}
__device__ __forceinline__ void stage4(const void* g, void* l) {
  __builtin_amdgcn_global_load_lds(
      (const __attribute__((address_space(1))) unsigned int*)g,
      (__attribute__((address_space(3))) unsigned int*)l, 4, 0, 0);
}

// ---------------------------------------------------------------------------
// prep kernel: block-range dispatch (unchanged from round 10, proven).
//   [0, 8192)      : quant_x  -> Aq int8 [8192][4096], sxT f32 [64][8192]
//   [8192, 12288)  : quant_w  -> Bq int8 [4096][4096], swT f32 [64][4096],
//                    luB bf16 [4096][32]
//   [12288, 12304) : ldT  (lora_down [K][R] -> bf16 ldT [R][K])
// ---------------------------------------------------------------------------
__global__ __launch_bounds__(256) void prep_kernel(
    const float* __restrict__ x, const float* __restrict__ smooth,
    const float* __restrict__ w, const float* __restrict__ lora_up,
    const float* __restrict__ ld,
    signed char* __restrict__ Aq, signed char* __restrict__ Bq,
    float* __restrict__ sxT, float* __restrict__ swT,
    bf16_t* __restrict__ luB, bf16_t* __restrict__ ldT) {
  const int bid = blockIdx.x;
  const int tid = threadIdx.x;

  if (bid < M_DIM) {                       // ---- quant_x ----
    const int row = bid;
    const int k0  = tid * 16;
    const float* xr = x + (size_t)row * K_DIM + k0;
    const float* sr = smooth + k0;

    float v[16];
#pragma unroll
    for (int i = 0; i < 4; ++i) {
      float4 xv = *(const float4*)(xr + i * 4);
      float4 sv = *(const float4*)(sr + i * 4);
      v[i*4+0] = xv.x * sv.x; v[i*4+1] = xv.y * sv.y;
      v[i*4+2] = xv.z * sv.z; v[i*4+3] = xv.w * sv.w;
    }
    float am = 0.f;
#pragma unroll
    for (int i = 0; i < 16; ++i) am = fmaxf(am, fabsf(v[i]));
    am = fmaxf(am, __shfl_xor(am, 1));
    am = fmaxf(am, __shfl_xor(am, 2));
    const float scale = fmaxf(am / QMAXF, 1e-8f);

    alignas(16) signed char o[16];
#pragma unroll
    for (int i = 0; i < 16; ++i) {
      float q = rintf(v[i] / scale);       // IEEE div + round-half-even = jnp
      q = fminf(fmaxf(q, -8.f), 7.f);
      o[i] = (signed char)(int)q;
    }
    *(uint4*)(Aq + (size_t)row * K_DIM + k0) = *(const uint4*)o;
    if ((tid & 3) == 0) sxT[(size_t)(tid >> 2) * M_DIM + row] = scale;

  } else if (bid < M_DIM + N_DIM) {        // ---- quant_w ----
    const int row = bid - M_DIM;
    const int k0  = tid * 16;
    const float* wr = w + (size_t)row * K_DIM + k0;

    float v[16];
#pragma unroll
    for (int i = 0; i < 4; ++i) {
      float4 wv = *(const float4*)(wr + i * 4);
      v[i*4+0] = wv.x; v[i*4+1] = wv.y; v[i*4+2] = wv.z; v[i*4+3] = wv.w;
    }
    float am = 0.f;
#pragma unroll
    for (int i = 0; i < 16; ++i) am = fmaxf(am, fabsf(v[i]));
    am = fmaxf(am, __shfl_xor(am, 1));
    am = fmaxf(am, __shfl_xor(am, 2));
    const float scale = fmaxf(am / QMAXF, 1e-8f);

    alignas(16) signed char o[16];
#pragma unroll
    for (int i = 0; i < 16; ++i) {
      float q = rintf(v[i] / scale);
      q = fminf(fmaxf(q, -8.f), 7.f);
      o[i] = (signed char)(int)q;
    }
    *(uint4*)(Bq + (size_t)row * K_DIM + k0) = *(const uint4*)o;
    if ((tid & 3) == 0) swT[(size_t)(tid >> 2) * N_DIM + row] = scale;
    if (tid < 32)
      luB[(size_t)row * R_DIM + tid] = __float2bfloat16(lora_up[row * R_DIM + tid]);

  } else {                                 // ---- ldT ----
    const int k = (bid - M_DIM - N_DIM) * 256 + tid;
    float v[R_DIM];
#pragma unroll
    for (int i = 0; i < R_DIM / 4; ++i) {
      float4 a = *(const float4*)(ld + (size_t)k * R_DIM + i * 4);
      v[i*4+0] = a.x; v[i*4+1] = a.y; v[i*4+2] = a.z; v[i*4+3] = a.w;
    }
#pragma unroll
    for (int r = 0; r < R_DIM; ++r)
      ldT[(size_t)r * K_DIM + k] = __float2bfloat16(v[r]);
  }
}

// ---------------------------------------------------------------------------
// t = (x*smooth) @ lora_down  [M x 32] via MFMA -> tB [8192][32] bf16.
// ---------------------------------------------------------------------------
__global__ __launch_bounds__(256) void lora_mfma_kernel(
    const float* __restrict__ x, const float* __restrict__ smooth,
    const bf16_t* __restrict__ ldT, bf16_t* __restrict__ tB) {
  const int tid  = threadIdx.x;
  const int w    = tid >> 6;
  const int lane = tid & 63;
  const int m0   = blockIdx.x * 32;

  const int mrow = m0 + (w >> 1) * 16 + (lane & 15);
  const int ncol = (w & 1) * 16 + (lane & 15);
  const float* xr = x + (size_t)mrow * K_DIM;
  const bf16_t* br = ldT + (size_t)ncol * K_DIM;

  f32x4 acc = {0.f, 0.f, 0.f, 0.f};
  union { bf16_t h[8]; bf16x8 v; } au;

  for (int k = 0; k < K_DIM; k += 32) {
    const int kf = k + (lane >> 4) * 8;
    float4 x0 = *(const float4*)(xr + kf);
    float4 x1 = *(const float4*)(xr + kf + 4);
    float4 s0 = *(const float4*)(smooth + kf);
    float4 s1 = *(const float4*)(smooth + kf + 4);
    au.h[0] = __float2bfloat16(x0.x * s0.x);
    au.h[1] = __float2bfloat16(x0.y * s0.y);
    au.h[2] = __float2bfloat16(x0.z * s0.z);
    au.h[3] = __float2bfloat16(x0.w * s0.w);
    au.h[4] = __float2bfloat16(x1.x * s1.x);
    au.h[5] = __float2bfloat16(x1.y * s1.y);
    au.h[6] = __float2bfloat16(x1.z * s1.z);
    au.h[7] = __float2bfloat16(x1.w * s1.w);
    bf16x8 bv = *(const bf16x8*)(br + kf);
    acc = __builtin_amdgcn_mfma_f32_16x16x32_bf16(au.v, bv, acc, 0, 0, 0);
  }

  const int orow = m0 + (w >> 1) * 16 + (lane >> 4) * 4;
#pragma unroll
  for (int q = 0; q < 4; ++q)
    tB[(size_t)(orow + q) * R_DIM + ncol] = __float2bfloat16(acc[q]);
}

// ---------------------------------------------------------------------------
// 128x128 int8 GEMM, BK=128 (2 groups/ktile), mfma_i32_32x32x32_i8.
// 8 waves (4M x 2N); wave tile 32x64 = 1x2 of 32x32 -> acc = 2 x f32x16
// (32 VGPR).  Total live regs ~110 < 128 arch VGPRs so acc AND the int
// temp ai live in VGPRs -- no v_accvgpr shuttle on the scale-apply path
// (round 10's 4xf32x16 acc was forced to AGPR -> ~1500 VALU/ktile).
// ZERO16 hoisted as the first MFMA's C operand (dst != C is legal) kills
// the per-tile zero-init movs.
// Schedule: round-9/10-proven one-interval slot-disjoint distance-1 ring.
// Swizzle: key(row)=(row^(row>>3))&7 both sides (0-conflict measured; key
// algebra identical under the new row formulas).
// LDS: A 2x16K | B 2x16K | sx 2x1K | sw 2x1K = 68 KiB dynamic.
// ---------------------------------------------------------------------------
__global__ __launch_bounds__(512, 2) void gemm_i8_kernel(
    const signed char* __restrict__ Aq, const signed char* __restrict__ Bq,
    const float* __restrict__ sxT, const float* __restrict__ swT,
    const bf16_t* __restrict__ tB, const bf16_t* __restrict__ luB,
    const float* __restrict__ bias, float* __restrict__ C) {
  extern __shared__ __align__(16) char lds[];   // 69632 B

  // XCD-aware swizzle: nwg = 2048, divisible by 8
  const int wg  = blockIdx.x;
  const int swz = (wg & 7) * 256 + (wg >> 3);
  const int bn  = swz & 31;    // 0..31 (128-col tiles)
  const int bm  = swz >> 5;    // 0..63 (128-row tiles)

  const int tid  = threadIdx.x;
  const int lane = tid & 63;
  const int wid  = tid >> 6;     // 0..7
  const int wm   = wid >> 1;     // 0..3  (32-row slice)
  const int wn   = wid & 1;      // 0..1  (64-col half)

  const int l31 = lane & 31;
  const int lh  = lane >> 5;
  const int l7  = lane & 7;
  const int rk  = l31 >> 3;

  // swizzle keys: key(row) = (row ^ (row>>3)) & 7
  const int keyA = l7 ^ ((wm * 4 + rk) & 7);            // A row = wm*32+l31
  const int keyB0 = l7 ^ (rk & 7);                      // B row = wn*64+ct*32+l31

  // staging: thread (sr,sl); source col granule = sl ^ key(sr); dest linear
  const int sr    = tid >> 3;                 // 0..63
  const int sl    = tid & 7;
  const int gbyte = (sl ^ ((sr ^ (sr >> 3)) & 7)) << 4;
  const signed char* Abase = Aq + (size_t)(bm * 128 + sr) * K_DIM + gbyte;
  const signed char* Bbase = Bq + (size_t)(bn * 128 + sr) * K_DIM + gbyte;

  char* ldsA  = lds;               // [2][16384]
  char* ldsB  = lds + 32768;       // [2][16384]
  char* ldsSX = lds + 65536;       // [2][1024]  f32 [2 groups][128 rows]
  char* ldsSW = lds + 67584;       // [2][1024]  f32 [2 groups][128 cols]

#define STAGE_ALL(buf, u) do {                                                 \
    _Pragma("unroll")                                                          \
    for (int j = 0; j < 2; ++j) {                                              \
      stage16(Abase + (size_t)(64 * j) * K_DIM + (u) * 128,                    \
              ldsA + (buf) * 16384 + j * 8192 + tid * 16);                     \
      stage16(Bbase + (size_t)(64 * j) * K_DIM + (u) * 128,                    \
              ldsB + (buf) * 16384 + j * 8192 + tid * 16);                     \
    }                                                                          \
    if (tid < 256)                                                             \
      stage4(sxT + (size_t)(2 * (u) + (tid >> 7)) * M_DIM + bm * 128 + (tid & 127), \
             ldsSX + (buf) * 1024 + tid * 4);                                  \
    else                                                                       \
      stage4(swT + (size_t)(2 * (u) + ((tid - 256) >> 7)) * N_DIM + bn * 128 + (tid & 127), \
             ldsSW + (buf) * 1024 + (tid - 256) * 4);                          \
  } while (0)

  f32x16 acc[2] = {};   // [ct]
  i32x4  aF[2];         // [kt]
  i32x4  bF[2][2];      // [ct][kt]
  float  swv[2];
  const i32x16 ZERO16 = {};

#define READ_G(g, cb) do {                                                     \
    const char* pa_ = ldsA + (cb) * 16384 + (wm * 32 + l31) * 128;             \
    _Pragma("unroll")                                                          \
    for (int kt = 0; kt < 2; ++kt)                                             \
      aF[kt] = *(const i32x4*)(pa_ +                                           \
        ((((g) * 4 + kt * 2 + lh) ^ keyA) << 4));                              \
    _Pragma("unroll")                                                          \
    for (int ct = 0; ct < 2; ++ct) {                                           \
      const char* pb_ = ldsB + (cb) * 16384 + (wn * 64 + ct * 32 + l31) * 128; \
      _Pragma("unroll")                                                        \
      for (int kt = 0; kt < 2; ++kt)                                           \
        bF[ct][kt] = *(const i32x4*)(pb_ +                                     \
          ((((g) * 4 + kt * 2 + lh) ^ keyB0 ^ ((ct) * 4)) << 4));              \
      swv[ct] = *(const float*)(ldsSW + (cb) * 1024 + (g) * 512 +              \
                                (wn * 64 + ct * 32 + l31) * 4);                \
    }                                                                          \
  } while (0)

#define COMPUTE_G(g, cb) do {                                                  \
    const float* sxp_ = (const float*)(ldsSX + (cb) * 1024 + (g) * 512) +      \
                        wm * 32 + lh * 4;                                      \
    _Pragma("unroll")                                                          \
    for (int ct = 0; ct < 2; ++ct) {                                           \
      i32x16 ai = __builtin_amdgcn_mfma_i32_32x32x32_i8(aF[0], bF[ct][0], ZERO16, 0, 0, 0); \
      ai = __builtin_amdgcn_mfma_i32_32x32x32_i8(aF[1], bF[ct][1], ai, 0, 0, 0); \
      _Pragma("unroll")                                                        \
      for (int q = 0; q < 4; ++q) {                                            \
        f32x4 sx4 = *(const f32x4*)(sxp_ + q * 8);                             \
        f32x4 p4 = sx4 * swv[ct];                                              \
        _Pragma("unroll")                                                      \
        for (int j = 0; j < 4; ++j)                                            \
          acc[ct][q * 4 + j] += p4[j] * (float)ai[q * 4 + j];                  \
      }                                                                        \
    }                                                                          \
  } while (0)

  // ---- prologue: stage ktile0 into buf0; drain; enter loop ----
  STAGE_ALL(0, 0);
  asm volatile("s_waitcnt vmcnt(0)" ::: "memory");
  __builtin_amdgcn_s_barrier();

  for (int u = 0; u < NT2; ++u) {
    const int cur = u & 1;
    READ_G(0, cur);
    if (u + 1 < NT2) STAGE_ALL(cur ^ 1, u + 1);   // other buffer: slot-disjoint
    asm volatile("s_waitcnt lgkmcnt(0)" ::: "memory");
    __builtin_amdgcn_s_setprio(1);
    COMPUTE_G(0, cur);
    __builtin_amdgcn_s_setprio(0);
    READ_G(1, cur);
    asm volatile("s_waitcnt lgkmcnt(0)" ::: "memory");
    __builtin_amdgcn_s_setprio(1);
    COMPUTE_G(1, cur);
    __builtin_amdgcn_s_setprio(0);
    asm volatile("s_waitcnt vmcnt(0)" ::: "memory");  // next ktile staged
    __builtin_amdgcn_s_barrier();
  }

  // ---- LoRA epilogue: acc += t_tile @ lu_tile^T (bf16 MFMA, K=32),
  //      fragments read directly from global (L2-resident, once/block) ----
  {
    bf16x8 tf[2], lf[2][2];   // [s], [ct][s]
    const bf16_t* pt = tB + (size_t)(bm * 128 + wm * 32 + l31) * R_DIM + lh * 8;
    tf[0] = *(const bf16x8*)(pt);
    tf[1] = *(const bf16x8*)(pt + 16);
#pragma unroll
    for (int ct = 0; ct < 2; ++ct) {
      const bf16_t* pl = luB + (size_t)(bn * 128 + wn * 64 + ct * 32 + l31) * R_DIM + lh * 8;
      lf[ct][0] = *(const bf16x8*)(pl);
      lf[ct][1] = *(const bf16x8*)(pl + 16);
    }
#pragma unroll
    for (int s = 0; s < 2; ++s)
#pragma unroll
      for (int ct = 0; ct < 2; ++ct)
        acc[ct] = __builtin_amdgcn_mfma_f32_32x32x16_bf16(
            tf[s], lf[ct][s], acc[ct], 0, 0, 0);
  }

  // ---- C write: 32x32 C/D: col=lane&31, row=(e&3)+8*(e>>2)+4*lh ----
#pragma unroll
  for (int ct = 0; ct < 2; ++ct) {
    const int gc = bn * 128 + wn * 64 + ct * 32 + l31;
    const float bv = bias[gc];
    const int gr0 = bm * 128 + wm * 32 + lh * 4;
#pragma unroll
    for (int e = 0; e < 16; ++e) {
      const int gr = gr0 + (e & 3) + 8 * (e >> 2);
      C[(size_t)gr * N_DIM + gc] = acc[ct][e] + bv;
    }
  }
#undef STAGE_ALL
#undef READ_G
#undef COMPUTE_G
}

// ---------------------------------------------------------------------------
extern "C" void kernel_launch(void* const* d_in, const int* in_sizes, int n_in,
                              void* d_out, int out_size, void* d_ws, size_t ws_size,
                              hipStream_t stream) {
  const float* x         = (const float*)d_in[0];
  const float* w_res     = (const float*)d_in[1];
  const float* lora_down = (const float*)d_in[2];
  const float* lora_up   = (const float*)d_in[3];
  const float* smooth    = (const float*)d_in[4];
  const float* b         = (const float*)d_in[5];
  float* out = (float*)d_out;

  // workspace carve-up (54.5 MB total)
  signed char* Aq  = (signed char*)d_ws;                       // 32 MB
  signed char* Bq  = Aq + (size_t)M_DIM * K_DIM;               // 16 MB
  float*       sxT = (float*)(Bq + (size_t)N_DIM * K_DIM);     // 2 MB [64][8192]
  float*       swT = sxT + (size_t)64 * M_DIM;                 // 1 MB [64][4096]
  bf16_t*      ldT = (bf16_t*)(swT + (size_t)64 * N_DIM);      // 256 KB [32][4096]
  bf16_t*      tB  = ldT + (size_t)R_DIM * K_DIM;              // 512 KB [8192][32]
  bf16_t*      luB = tB + (size_t)M_DIM * R_DIM;               // 256 KB [4096][32]

  hipFuncSetAttribute((const void*)gemm_i8_kernel,
                      hipFuncAttributeMaxDynamicSharedMemorySize, 69632);

  prep_kernel<<<M_DIM + N_DIM + K_DIM / 256, 256, 0, stream>>>(
      x, smooth, w_res, lora_up, lora_down, Aq, Bq, sxT, swT, luB, ldT);
  lora_mfma_kernel<<<M_DIM / 32, 256, 0, stream>>>(x, smooth, ldT, tB);
  gemm_i8_kernel<<<(M_DIM / 128) * (N_DIM / 128), 512, 69632, stream>>>(
      Aq, Bq, sxT, swT, tB, luB, b, out);
}

// Round 12
// 391.632 us; speedup vs baseline: 5.3537x; 1.0719x over previous
//
#include <hip/hip_runtime.h>
#include <hip/hip_bf16.h>
#include <stdint.h>

#define M_DIM 8192
#define N_DIM 4096
#define K_DIM 4096
#define R_DIM 32
#define KPAD  4160   // 4096 quant cols + 32 lora cols + 32 zero pad = 65 * 64
#define NT    65     // K-tiles of 64
#define QMAXF 7.0f

using bf16_t = __hip_bfloat16;
typedef __attribute__((ext_vector_type(4)))  float f32x4;
typedef __attribute__((ext_vector_type(16))) float f32x16;
typedef __attribute__((ext_vector_type(8)))  short bf16x8;

// ---------------------------------------------------------------------------
// async global->LDS 16B stage (LDS dest = wave-uniform base + lane*16)
// ---------------------------------------------------------------------------
__device__ __forceinline__ void stage16(const void* g, void* l) {
  __builtin_amdgcn_global_load_lds(
      (const __attribute__((address_space(1))) unsigned int*)g,
      (__attribute__((address_space(3))) unsigned int*)l, 16, 0, 0);
}

// ---------------------------------------------------------------------------
// prep kernel: block-range dispatch of three independent jobs.
//   blocks [0, 8192)      : quant_x  -> Ap cols 0..4095, zero pad 4128..4159
//   blocks [8192, 12288)  : quant_w  -> Bp cols 0..4095, lora_up 4096..4127, pad
//   blocks [12288, 12304) : ldT      (lora_down [K][R] -> bf16 ldT [R][K])
// ---------------------------------------------------------------------------
__global__ __launch_bounds__(256) void prep_kernel(
    const float* __restrict__ x, const float* __restrict__ smooth,
    const float* __restrict__ w, const float* __restrict__ lora_up,
    const float* __restrict__ ld,
    bf16_t* __restrict__ Ap, bf16_t* __restrict__ Bp,
    bf16_t* __restrict__ ldT) {
  const int bid = blockIdx.x;
  const int tid = threadIdx.x;

  if (bid < M_DIM) {                       // ---- quant_x ----
    const int row = bid;
    const int k0  = tid * 16;
    const float* xr = x + (size_t)row * K_DIM + k0;
    const float* sr = smooth + k0;

    float v[16];
#pragma unroll
    for (int i = 0; i < 4; ++i) {
      float4 xv = *(const float4*)(xr + i * 4);
      float4 sv = *(const float4*)(sr + i * 4);
      v[i*4+0] = xv.x * sv.x; v[i*4+1] = xv.y * sv.y;
      v[i*4+2] = xv.z * sv.z; v[i*4+3] = xv.w * sv.w;
    }
    float am = 0.f;
#pragma unroll
    for (int i = 0; i < 16; ++i) am = fmaxf(am, fabsf(v[i]));
    am = fmaxf(am, __shfl_xor(am, 1));
    am = fmaxf(am, __shfl_xor(am, 2));
    const float scale = fmaxf(am / QMAXF, 1e-8f);

    alignas(16) bf16_t o[16];
#pragma unroll
    for (int i = 0; i < 16; ++i) {
      float q = rintf(v[i] / scale);       // IEEE div + round-half-even = jnp
      q = fminf(fmaxf(q, -8.f), 7.f);
      o[i] = __float2bfloat16(q * scale);
    }
    bf16_t* dst = Ap + (size_t)row * KPAD + k0;
    ((uint4*)dst)[0] = ((uint4*)o)[0];
    ((uint4*)dst)[1] = ((uint4*)o)[1];
    if (tid < 32) Ap[(size_t)row * KPAD + 4128 + tid] = __float2bfloat16(0.f);

  } else if (bid < M_DIM + N_DIM) {        // ---- quant_w ----
    const int row = bid - M_DIM;
    const int k0  = tid * 16;
    const float* wr = w + (size_t)row * K_DIM + k0;

    float v[16];
#pragma unroll
    for (int i = 0; i < 4; ++i) {
      float4 wv = *(const float4*)(wr + i * 4);
      v[i*4+0] = wv.x; v[i*4+1] = wv.y; v[i*4+2] = wv.z; v[i*4+3] = wv.w;
    }
    float am = 0.f;
#pragma unroll
    for (int i = 0; i < 16; ++i) am = fmaxf(am, fabsf(v[i]));
    am = fmaxf(am, __shfl_xor(am, 1));
    am = fmaxf(am, __shfl_xor(am, 2));
    const float scale = fmaxf(am / QMAXF, 1e-8f);

    alignas(16) bf16_t o[16];
#pragma unroll
    for (int i = 0; i < 16; ++i) {
      float q = rintf(v[i] / scale);
      q = fminf(fmaxf(q, -8.f), 7.f);
      o[i] = __float2bfloat16(q * scale);
    }
    bf16_t* dst = Bp + (size_t)row * KPAD + k0;
    ((uint4*)dst)[0] = ((uint4*)o)[0];
    ((uint4*)dst)[1] = ((uint4*)o)[1];
    if (tid < 32) {
      Bp[(size_t)row * KPAD + 4096 + tid] = __float2bfloat16(lora_up[row * R_DIM + tid]);
    } else if (tid < 64) {
      Bp[(size_t)row * KPAD + 4096 + tid] = __float2bfloat16(0.f);
    }

  } else {                                 // ---- ldT ----
    const int k = (bid - M_DIM - N_DIM) * 256 + tid;
    float v[R_DIM];
#pragma unroll
    for (int i = 0; i < R_DIM / 4; ++i) {
      float4 a = *(const float4*)(ld + (size_t)k * R_DIM + i * 4);
      v[i*4+0] = a.x; v[i*4+1] = a.y; v[i*4+2] = a.z; v[i*4+3] = a.w;
    }
#pragma unroll
    for (int r = 0; r < R_DIM; ++r)
      ldT[(size_t)r * K_DIM + k] = __float2bfloat16(v[r]);
  }
}

// ---------------------------------------------------------------------------
// t = (x*smooth) @ lora_down  [M x 32] via MFMA -> Ap cols 4096..4127.
// ---------------------------------------------------------------------------
__global__ __launch_bounds__(256) void lora_mfma_kernel(
    const float* __restrict__ x, const float* __restrict__ smooth,
    const bf16_t* __restrict__ ldT, bf16_t* __restrict__ Ap) {
  const int tid  = threadIdx.x;
  const int w    = tid >> 6;
  const int lane = tid & 63;
  const int m0   = blockIdx.x * 32;

  const int mrow = m0 + (w >> 1) * 16 + (lane & 15);
  const int ncol = (w & 1) * 16 + (lane & 15);
  const float* xr = x + (size_t)mrow * K_DIM;
  const bf16_t* br = ldT + (size_t)ncol * K_DIM;

  f32x4 acc = {0.f, 0.f, 0.f, 0.f};
  union { bf16_t h[8]; bf16x8 v; } au;

  for (int k = 0; k < K_DIM; k += 32) {
    const int kf = k + (lane >> 4) * 8;
    float4 x0 = *(const float4*)(xr + kf);
    float4 x1 = *(const float4*)(xr + kf + 4);
    float4 s0 = *(const float4*)(smooth + kf);
    float4 s1 = *(const float4*)(smooth + kf + 4);
    au.h[0] = __float2bfloat16(x0.x * s0.x);
    au.h[1] = __float2bfloat16(x0.y * s0.y);
    au.h[2] = __float2bfloat16(x0.z * s0.z);
    au.h[3] = __float2bfloat16(x0.w * s0.w);
    au.h[4] = __float2bfloat16(x1.x * s1.x);
    au.h[5] = __float2bfloat16(x1.y * s1.y);
    au.h[6] = __float2bfloat16(x1.z * s1.z);
    au.h[7] = __float2bfloat16(x1.w * s1.w);
    bf16x8 bv = *(const bf16x8*)(br + kf);
    acc = __builtin_amdgcn_mfma_f32_16x16x32_bf16(au.v, bv, acc, 0, 0, 0);
  }

  const int orow = m0 + (w >> 1) * 16 + (lane >> 4) * 4;
  const int ocol = 4096 + ncol;
#pragma unroll
  for (int q = 0; q < 4; ++q)
    Ap[(size_t)(orow + q) * KPAD + ocol] = __float2bfloat16(acc[q]);
}

// ---------------------------------------------------------------------------
// 256x256x64 bf16 GEMM, SINGLE-INTERVAL RING (structure proven on HW in
// rounds 9-11 with int8; layout/swizzle/epilogue proven in rounds 5-7).
// 8 waves (2M x 4N); wave tile 128x64 = 4rt x 2ct of 32x32
// (mfma_f32_32x32x16_bf16, acc 8 x f32x16 native AGPR -- zero VALU in loop).
// LDS: plain row-major A[256][64] + B[256][64] bf16, double-buffered = 128 K.
// Per ktile (ONE barrier, was 4 in round 5):
//   READ all 24 frags from buf cur      (lgkm; issues first)
//   STAGE ktile u+1 -> buf cur^1        (vmcnt; slot-disjoint by buffer)
//   lgkm(0); 32 x MFMA (setprio-wrapped)
//   vmcnt(0); s_barrier                 (stage drained under MFMA cluster)
// Wave-overlap: w0's MFMA covers w1's LDS reads (2 waves/SIMD).
// Swizzle: granule ^= (row ^ (row>>3)) & 7 both sides (0-conflict, r7).
// ---------------------------------------------------------------------------
__global__ __launch_bounds__(512, 2) void gemm_kernel(
    const bf16_t* __restrict__ A, const bf16_t* __restrict__ B,
    const float* __restrict__ bias, float* __restrict__ C) {
  extern __shared__ __align__(16) bf16_t lds[];   // 65536 elems = 128 KiB

  // XCD-aware swizzle: nwg = 512, divisible by 8
  const int wg  = blockIdx.x;
  const int swz = (wg & 7) * 64 + (wg >> 3);
  const int bn  = swz & 15;    // 0..15
  const int bm  = swz >> 4;    // 0..31

  const int tid  = threadIdx.x;
  const int lane = tid & 63;
  const int wid  = tid >> 6;     // 0..7
  const int wm   = wid >> 2;     // 0..1  (128-row half)
  const int wn   = wid & 3;      // 0..3  (64-col quarter)

  const int l31 = lane & 31;
  const int lh  = lane >> 5;
  const int l7  = lane & 7;
  const int rk  = l31 >> 3;

  // staging: thread (sr, sl) stages rows sr+64j, granule sl, source granule
  // sl ^ key(row);  key(row) = (row ^ (row>>3)) & 7 is invariant under +64j.
  const int sr   = tid >> 3;                 // 0..63
  const int sl   = tid & 7;
  const int gcol = (sl ^ ((sr ^ (sr >> 3)) & 7)) * 8;
  const bf16_t* Ag = A + (size_t)(bm * 256 + sr) * KPAD + gcol;
  const bf16_t* Bg = B + (size_t)(bn * 256 + sr) * KPAD + gcol;

#define STAGE_ALL(buf, u) do {                                                 \
    _Pragma("unroll")                                                          \
    for (int j = 0; j < 4; ++j) {                                              \
      stage16(Ag + (size_t)(j * 64) * KPAD + (u) * 64,                         \
              lds + (buf) * 32768 + j * 4096 + tid * 8);                       \
      stage16(Bg + (size_t)(j * 64) * KPAD + (u) * 64,                         \
              lds + (buf) * 32768 + 16384 + j * 4096 + tid * 8);               \
    }                                                                          \
  } while (0)

  f32x16 acc[8] = {};   // [rt*2 + ct]
  bf16x8 aF[4][4];      // [rt][kt]
  bf16x8 bF[2][4];      // [ct][kt]

#define READ_ALL(cb) do {                                                      \
    _Pragma("unroll")                                                          \
    for (int rt = 0; rt < 4; ++rt) {                                           \
      const bf16_t* pa_ = lds + (cb) * 32768 + (wm * 128 + rt * 32 + l31) * 64;\
      const int ka_ = l7 ^ ((rt * 4 + rk) & 7);                                \
      _Pragma("unroll")                                                        \
      for (int kt = 0; kt < 4; ++kt)                                           \
        aF[rt][kt] = *(const bf16x8*)(pa_ + ((kt * 2 + lh) ^ ka_) * 8);        \
    }                                                                          \
    _Pragma("unroll")                                                          \
    for (int ct = 0; ct < 2; ++ct) {                                           \
      const bf16_t* pb_ = lds + (cb) * 32768 + 16384 +                         \
                          (wn * 64 + ct * 32 + l31) * 64;                      \
      const int kb_ = l7 ^ ((ct * 4 + rk) & 7);                                \
      _Pragma("unroll")                                                        \
      for (int kt = 0; kt < 4; ++kt)                                           \
        bF[ct][kt] = *(const bf16x8*)(pb_ + ((kt * 2 + lh) ^ kb_) * 8);        \
    }                                                                          \
  } while (0)

#define MFMA_ALL() do {                                                        \
    _Pragma("unroll")                                                          \
    for (int kt = 0; kt < 4; ++kt)                                             \
      _Pragma("unroll")                                                        \
      for (int rt = 0; rt < 4; ++rt)                                           \
        _Pragma("unroll")                                                      \
        for (int ct = 0; ct < 2; ++ct)                                         \
          acc[rt * 2 + ct] = __builtin_amdgcn_mfma_f32_32x32x16_bf16(          \
              aF[rt][kt], bF[ct][kt], acc[rt * 2 + ct], 0, 0, 0);              \
  } while (0)

  // ---- prologue: stage ktile0 into buf0; drain; enter ring ----
  STAGE_ALL(0, 0);
  asm volatile("s_waitcnt vmcnt(0)" ::: "memory");
  __builtin_amdgcn_s_barrier();

  for (int u = 0; u < NT; ++u) {
    const int cur = u & 1;
    READ_ALL(cur);
    if (u + 1 < NT) STAGE_ALL(cur ^ 1, u + 1);   // other buffer: slot-disjoint
    asm volatile("s_waitcnt lgkmcnt(0)" ::: "memory");
    __builtin_amdgcn_s_setprio(1);
    MFMA_ALL();
    __builtin_amdgcn_s_setprio(0);
    asm volatile("s_waitcnt vmcnt(0)" ::: "memory");  // next ktile staged
    __builtin_amdgcn_s_barrier();
  }

  // ---- epilogue: 32x32 C/D: col=lane&31, row=(e&3)+8*(e>>2)+4*lh ----
#pragma unroll
  for (int rt = 0; rt < 4; ++rt) {
#pragma unroll
    for (int ct = 0; ct < 2; ++ct) {
      const int gc = bn * 256 + wn * 64 + ct * 32 + l31;
      const float bv = bias[gc];
      const int gr0 = bm * 256 + wm * 128 + rt * 32 + lh * 4;
#pragma unroll
      for (int e = 0; e < 16; ++e) {
        const int gr = gr0 + (e & 3) + 8 * (e >> 2);
        C[(size_t)gr * N_DIM + gc] = acc[rt * 2 + ct][e] + bv;
      }
    }
  }
#undef STAGE_ALL
#undef READ_ALL
#undef MFMA_ALL
}

// ---------------------------------------------------------------------------
extern "C" void kernel_launch(void* const* d_in, const int* in_sizes, int n_in,
                              void* d_out, int out_size, void* d_ws, size_t ws_size,
                              hipStream_t stream) {
  const float* x         = (const float*)d_in[0];
  const float* w_res     = (const float*)d_in[1];
  const float* lora_down = (const float*)d_in[2];
  const float* lora_up   = (const float*)d_in[3];
  const float* smooth    = (const float*)d_in[4];
  const float* b         = (const float*)d_in[5];
  float* out = (float*)d_out;

  // workspace: Ap [M][KPAD] bf16 (68.2 MB), Bp [N][KPAD] bf16 (34.1 MB),
  // ldT [R][K] bf16 (256 KB)
  bf16_t* Ap  = (bf16_t*)d_ws;
  bf16_t* Bp  = Ap + (size_t)M_DIM * KPAD;
  bf16_t* ldT = Bp + (size_t)N_DIM * KPAD;

  // allow 128 KiB dynamic LDS (idempotent, host-side, capture-safe)
  hipFuncSetAttribute((const void*)gemm_kernel,
                      hipFuncAttributeMaxDynamicSharedMemorySize, 131072);

  prep_kernel<<<M_DIM + N_DIM + K_DIM / 256, 256, 0, stream>>>(
      x, smooth, w_res, lora_up, lora_down, Ap, Bp, ldT);
  lora_mfma_kernel<<<M_DIM / 32, 256, 0, stream>>>(x, smooth, ldT, Ap);
  gemm_kernel<<<(M_DIM / 256) * (N_DIM / 256), 512, 131072, stream>>>(Ap, Bp, b, out);
}

// Round 13
// 357.710 us; speedup vs baseline: 5.8614x; 1.0948x over previous
//
#include <hip/hip_runtime.h>
#include <hip/hip_bf16.h>
#include <stdint.h>

#define M_DIM 8192
#define N_DIM 4096
#define K_DIM 4096
#define R_DIM 32
#define KPAD  4160   // 4096 quant cols + 32 lora cols + 32 zero pad = 65 * 64
#define NT    65     // K-tiles of 64
#define QMAXF 7.0f

using bf16_t = __hip_bfloat16;
typedef __attribute__((ext_vector_type(4))) float f32x4;
typedef __attribute__((ext_vector_type(8))) short bf16x8;

// ---------------------------------------------------------------------------
// async global->LDS 16B stage (LDS dest = wave-uniform base + lane*16)
// ---------------------------------------------------------------------------
__device__ __forceinline__ void stage16(const void* g, void* l) {
#if defined(__has_builtin) && __has_builtin(__builtin_amdgcn_global_load_lds)
  __builtin_amdgcn_global_load_lds(
      (const __attribute__((address_space(1))) unsigned int*)g,
      (__attribute__((address_space(3))) unsigned int*)l, 16, 0, 0);
#else
  *(uint4*)l = *(const uint4*)g;
#endif
}

// ---------------------------------------------------------------------------
// prep kernel: block-range dispatch of three independent jobs.
//   blocks [0, 8192)      : quant_x  -> Ap cols 0..4095, zero pad 4128..4159
//   blocks [8192, 12288)  : quant_w  -> Bp cols 0..4095, lora_up 4096..4127, pad
//   blocks [12288, 12304) : ldT      (lora_down [K][R] -> bf16 ldT [R][K])
// ---------------------------------------------------------------------------
__global__ __launch_bounds__(256) void prep_kernel(
    const float* __restrict__ x, const float* __restrict__ smooth,
    const float* __restrict__ w, const float* __restrict__ lora_up,
    const float* __restrict__ ld,
    bf16_t* __restrict__ Ap, bf16_t* __restrict__ Bp,
    bf16_t* __restrict__ ldT) {
  const int bid = blockIdx.x;
  const int tid = threadIdx.x;

  if (bid < M_DIM) {                       // ---- quant_x ----
    const int row = bid;
    const int k0  = tid * 16;
    const float* xr = x + (size_t)row * K_DIM + k0;
    const float* sr = smooth + k0;

    float v[16];
#pragma unroll
    for (int i = 0; i < 4; ++i) {
      float4 xv = *(const float4*)(xr + i * 4);
      float4 sv = *(const float4*)(sr + i * 4);
      v[i*4+0] = xv.x * sv.x; v[i*4+1] = xv.y * sv.y;
      v[i*4+2] = xv.z * sv.z; v[i*4+3] = xv.w * sv.w;
    }
    float am = 0.f;
#pragma unroll
    for (int i = 0; i < 16; ++i) am = fmaxf(am, fabsf(v[i]));
    am = fmaxf(am, __shfl_xor(am, 1));
    am = fmaxf(am, __shfl_xor(am, 2));
    const float scale = fmaxf(am / QMAXF, 1e-8f);

    alignas(16) bf16_t o[16];
#pragma unroll
    for (int i = 0; i < 16; ++i) {
      float q = rintf(v[i] / scale);       // IEEE div + round-half-even = jnp
      q = fminf(fmaxf(q, -8.f), 7.f);
      o[i] = __float2bfloat16(q * scale);
    }
    bf16_t* dst = Ap + (size_t)row * KPAD + k0;
    ((uint4*)dst)[0] = ((uint4*)o)[0];
    ((uint4*)dst)[1] = ((uint4*)o)[1];
    if (tid < 32) Ap[(size_t)row * KPAD + 4128 + tid] = __float2bfloat16(0.f);

  } else if (bid < M_DIM + N_DIM) {        // ---- quant_w ----
    const int row = bid - M_DIM;
    const int k0  = tid * 16;
    const float* wr = w + (size_t)row * K_DIM + k0;

    float v[16];
#pragma unroll
    for (int i = 0; i < 4; ++i) {
      float4 wv = *(const float4*)(wr + i * 4);
      v[i*4+0] = wv.x; v[i*4+1] = wv.y; v[i*4+2] = wv.z; v[i*4+3] = wv.w;
    }
    float am = 0.f;
#pragma unroll
    for (int i = 0; i < 16; ++i) am = fmaxf(am, fabsf(v[i]));
    am = fmaxf(am, __shfl_xor(am, 1));
    am = fmaxf(am, __shfl_xor(am, 2));
    const float scale = fmaxf(am / QMAXF, 1e-8f);

    alignas(16) bf16_t o[16];
#pragma unroll
    for (int i = 0; i < 16; ++i) {
      float q = rintf(v[i] / scale);
      q = fminf(fmaxf(q, -8.f), 7.f);
      o[i] = __float2bfloat16(q * scale);
    }
    bf16_t* dst = Bp + (size_t)row * KPAD + k0;
    ((uint4*)dst)[0] = ((uint4*)o)[0];
    ((uint4*)dst)[1] = ((uint4*)o)[1];
    if (tid < 32) {
      Bp[(size_t)row * KPAD + 4096 + tid] = __float2bfloat16(lora_up[row * R_DIM + tid]);
    } else if (tid < 64) {
      Bp[(size_t)row * KPAD + 4096 + tid] = __float2bfloat16(0.f);
    }

  } else {                                 // ---- ldT ----
    const int k = (bid - M_DIM - N_DIM) * 256 + tid;
    float v[R_DIM];
#pragma unroll
    for (int i = 0; i < R_DIM / 4; ++i) {
      float4 a = *(const float4*)(ld + (size_t)k * R_DIM + i * 4);
      v[i*4+0] = a.x; v[i*4+1] = a.y; v[i*4+2] = a.z; v[i*4+3] = a.w;
    }
#pragma unroll
    for (int r = 0; r < R_DIM; ++r)
      ldT[(size_t)r * K_DIM + k] = __float2bfloat16(v[r]);
  }
}

// ---------------------------------------------------------------------------
// t = (x*smooth) @ lora_down  [M x 32] via MFMA -> Ap cols 4096..4127.
// ---------------------------------------------------------------------------
__global__ __launch_bounds__(256) void lora_mfma_kernel(
    const float* __restrict__ x, const float* __restrict__ smooth,
    const bf16_t* __restrict__ ldT, bf16_t* __restrict__ Ap) {
  const int tid  = threadIdx.x;
  const int w    = tid >> 6;
  const int lane = tid & 63;
  const int m0   = blockIdx.x * 32;

  const int mrow = m0 + (w >> 1) * 16 + (lane & 15);
  const int ncol = (w & 1) * 16 + (lane & 15);
  const float* xr = x + (size_t)mrow * K_DIM;
  const bf16_t* br = ldT + (size_t)ncol * K_DIM;

  f32x4 acc = {0.f, 0.f, 0.f, 0.f};
  union { bf16_t h[8]; bf16x8 v; } au;

  for (int k = 0; k < K_DIM; k += 32) {
    const int kf = k + (lane >> 4) * 8;
    float4 x0 = *(const float4*)(xr + kf);
    float4 x1 = *(const float4*)(xr + kf + 4);
    float4 s0 = *(const float4*)(smooth + kf);
    float4 s1 = *(const float4*)(smooth + kf + 4);
    au.h[0] = __float2bfloat16(x0.x * s0.x);
    au.h[1] = __float2bfloat16(x0.y * s0.y);
    au.h[2] = __float2bfloat16(x0.z * s0.z);
    au.h[3] = __float2bfloat16(x0.w * s0.w);
    au.h[4] = __float2bfloat16(x1.x * s1.x);
    au.h[5] = __float2bfloat16(x1.y * s1.y);
    au.h[6] = __float2bfloat16(x1.z * s1.z);
    au.h[7] = __float2bfloat16(x1.w * s1.w);
    bf16x8 bv = *(const bf16x8*)(br + kf);
    acc = __builtin_amdgcn_mfma_f32_16x16x32_bf16(au.v, bv, acc, 0, 0, 0);
  }

  const int orow = m0 + (w >> 1) * 16 + (lane >> 4) * 4;
  const int ocol = 4096 + ncol;
#pragma unroll
  for (int q = 0; q < 4; ++q)
    Ap[(size_t)(orow + q) * KPAD + ocol] = __float2bfloat16(acc[q]);
}

// ---------------------------------------------------------------------------
// 256x256x64 8-phase GEMM (session champion, 255 us / 1094 TF measured):
// A-fragments pipelined one phase ahead (aA/aB ping-pong), B-fragments
// single-set re-read once per ktile at P4's tail after the MFMA cluster
// (WAR-safe via in-order issue; LDS data valid per the vmcnt(6) ring).
// Stage ring: P1: A2(u+1)->buf^1 | P2: B1(u+2)->buf | P3: B2(u+2)->buf |
//   P4: A1(u+2)->buf + vmcnt(6)  (tail: vmcnt(0)).  vmcnt(6) at P4(u)
//   retires exactly all of ktile u+1 (queue 6+2+6=14 -> retire 8).
// A quadrant-major LDS (lds_row = q*64 + wm*32 + r).  Swizzle: 16B granule
// ^= (row&7) on stage-source and ds_read (measured 0 conflicts).
// ---------------------------------------------------------------------------
__global__ __launch_bounds__(512, 2) void gemm_kernel(
    const bf16_t* __restrict__ A, const bf16_t* __restrict__ B,
    const float* __restrict__ bias, float* __restrict__ C) {
  extern __shared__ __align__(16) bf16_t lds[];   // 65536 elems = 128 KiB

  // XCD-aware swizzle: nwg = 512, divisible by 8
  const int wg  = blockIdx.x;
  const int swz = (wg & 7) * 64 + (wg >> 3);
  const int bn  = swz & 15;    // 0..15
  const int bm  = swz >> 4;    // 0..31

  const int tid  = threadIdx.x;
  const int lane = tid & 63;
  const int wid  = tid >> 6;     // 0..7
  const int wm   = wid >> 2;     // 0..1
  const int wn   = wid & 3;      // 0..3

  const int lr = lane & 15;      // frag row within 16
  const int lg = lane >> 4;      // k-granule subindex 0..3
  const int l7 = lane & 7;
  const int gk0 = ((0 + lg) ^ l7) * 8;   // swizzled elem offset, k-half 0
  const int gk1 = ((4 + lg) ^ l7) * 8;   // k-half 1

  // staging geometry
  const int sr   = tid >> 3;                 // 0..63
  const int sl   = tid & 7;                  // granule slot
  const int gcol = (sl ^ (sr & 7)) * 8;      // inverse-swizzled source col
  const bf16_t* Abase = A + (size_t)(bm * 256 + ((sr >> 5) & 1) * 128 + (sr & 31)) * KPAD + gcol;
  const bf16_t* Bbase = B + (size_t)(bn * 256 + sr) * KPAD + gcol;
  bf16_t* ldsb = lds;

#define STAGE_A(buf, h, kt) do {                                               \
    stage16(Abase + (size_t)((h) * 2 + 0) * 32 * KPAD + (kt) * 64,             \
            ldsb + (buf) * 32768 + (h) * 8192 + 0 * 4096 + tid * 8);           \
    stage16(Abase + (size_t)((h) * 2 + 1) * 32 * KPAD + (kt) * 64,             \
            ldsb + (buf) * 32768 + (h) * 8192 + 1 * 4096 + tid * 8);           \
  } while (0)
#define STAGE_B(buf, h, kt) do {                                               \
    stage16(Bbase + (size_t)((h) * 128 + 0) * KPAD + (kt) * 64,                \
            ldsb + (buf) * 32768 + 16384 + (h) * 8192 + 0 * 4096 + tid * 8);   \
    stage16(Bbase + (size_t)((h) * 128 + 64) * KPAD + (kt) * 64,               \
            ldsb + (buf) * 32768 + 16384 + (h) * 8192 + 1 * 4096 + tid * 8);   \
  } while (0)

  f32x4  acc[8][4] = {};
  bf16x8 aA[2][2];   // A-frag ping (quadrants 0,2)
  bf16x8 aB[2][2];   // A-frag pong (quadrants 1,3)
  bf16x8 bF[4][2];   // B-frags, one set, reloaded per ktile

#define LOAD_A(DST, q, cb) do {                                                \
    const bf16_t* pa_ = ldsb + (cb) * 32768 + ((q) * 64 + wm * 32 + lr) * 64;  \
    DST[0][0] = *(const bf16x8*)(pa_ + gk0);                                   \
    DST[0][1] = *(const bf16x8*)(pa_ + gk1);                                   \
    DST[1][0] = *(const bf16x8*)(pa_ + 1024 + gk0);                            \
    DST[1][1] = *(const bf16x8*)(pa_ + 1024 + gk1);                            \
  } while (0)
#define LOAD_BN(nbuf) do {                                                     \
    _Pragma("unroll")                                                          \
    for (int j = 0; j < 4; ++j) {                                              \
      const bf16_t* pb_ = ldsb + (nbuf) * 32768 + 16384 + (wn * 64 + j * 16 + lr) * 64; \
      bF[j][0] = *(const bf16x8*)(pb_ + gk0);                                  \
      bF[j][1] = *(const bf16x8*)(pb_ + gk1);                                  \
    }                                                                          \
  } while (0)
#define MFMA_Q(q, AARR) do {                                                   \
    _Pragma("unroll")                                                          \
    for (int i = 0; i < 2; ++i)                                                \
      _Pragma("unroll")                                                        \
      for (int j = 0; j < 4; ++j) {                                            \
        acc[(q)*2+i][j] = __builtin_amdgcn_mfma_f32_16x16x32_bf16(             \
            AARR[i][0], bF[j][0], acc[(q)*2+i][j], 0, 0, 0);                   \
        acc[(q)*2+i][j] = __builtin_amdgcn_mfma_f32_16x16x32_bf16(             \
            AARR[i][1], bF[j][1], acc[(q)*2+i][j], 0, 0, 0);                   \
      }                                                                        \
  } while (0)

#define KTILE(u, cur) do {                                                     \
    /* ---- P1 ---- */                                                         \
    if ((u) + 1 < NT) STAGE_A((cur) ^ 1, 1, (u) + 1);                          \
    __builtin_amdgcn_s_barrier();                                              \
    asm volatile("s_waitcnt lgkmcnt(0)" ::: "memory");                         \
    __builtin_amdgcn_sched_barrier(0);                                         \
    LOAD_A(aB, 1, cur);                                                        \
    __builtin_amdgcn_sched_barrier(0);                                         \
    __builtin_amdgcn_s_setprio(1);                                             \
    MFMA_Q(0, aA);                                                             \
    __builtin_amdgcn_s_setprio(0);                                             \
    __builtin_amdgcn_s_barrier();                                              \
    /* ---- P2 ---- */                                                         \
    if ((u) + 2 < NT) STAGE_B(cur, 0, (u) + 2);                                \
    __builtin_amdgcn_s_barrier();                                              \
    asm volatile("s_waitcnt lgkmcnt(0)" ::: "memory");                         \
    __builtin_amdgcn_sched_barrier(0);                                         \
    LOAD_A(aA, 2, cur);                                                        \
    __builtin_amdgcn_sched_barrier(0);                                         \
    __builtin_amdgcn_s_setprio(1);                                             \
    MFMA_Q(1, aB);                                                             \
    __builtin_amdgcn_s_setprio(0);                                             \
    __builtin_amdgcn_s_barrier();                                              \
    /* ---- P3 ---- */                                                         \
    if ((u) + 2 < NT) STAGE_B(cur, 1, (u) + 2);                                \
    __builtin_amdgcn_s_barrier();                                              \
    asm volatile("s_waitcnt lgkmcnt(0)" ::: "memory");                         \
    __builtin_amdgcn_sched_barrier(0);                                         \
    LOAD_A(aB, 3, cur);                                                        \
    __builtin_amdgcn_sched_barrier(0);                                         \
    __builtin_amdgcn_s_setprio(1);                                             \
    MFMA_Q(2, aA);                                                             \
    __builtin_amdgcn_s_setprio(0);                                             \
    __builtin_amdgcn_s_barrier();                                              \
    /* ---- P4 ---- */                                                         \
    if ((u) + 2 < NT) {                                                        \
      STAGE_A(cur, 0, (u) + 2);                                                \
      asm volatile("s_waitcnt vmcnt(6)" ::: "memory");                         \
    } else {                                                                   \
      asm volatile("s_waitcnt vmcnt(0)" ::: "memory");                         \
    }                                                                          \
    __builtin_amdgcn_s_barrier();                                              \
    asm volatile("s_waitcnt lgkmcnt(0)" ::: "memory");                         \
    __builtin_amdgcn_sched_barrier(0);                                         \
    if ((u) + 1 < NT) LOAD_A(aA, 0, (cur) ^ 1);                                \
    __builtin_amdgcn_sched_barrier(0);                                         \
    __builtin_amdgcn_s_setprio(1);                                             \
    MFMA_Q(3, aB);                                                             \
    __builtin_amdgcn_s_setprio(0);                                             \
    __builtin_amdgcn_sched_barrier(0);                                         \
    if ((u) + 1 < NT) LOAD_BN((cur) ^ 1);                                      \
    __builtin_amdgcn_s_barrier();                                              \
  } while (0)

  // ---- prologue: stage ktile0 fully + ktile1's B1,B2,A1; wait ktile0;
  //      preload B(0) and A-q0(0) fragment registers ----
  STAGE_B(0, 0, 0); STAGE_B(0, 1, 0); STAGE_A(0, 0, 0); STAGE_A(0, 1, 0);
  STAGE_B(1, 0, 1); STAGE_B(1, 1, 1); STAGE_A(1, 0, 1);
  asm volatile("s_waitcnt vmcnt(6)" ::: "memory");
  __builtin_amdgcn_s_barrier();
  LOAD_BN(0);
  LOAD_A(aA, 0, 0);

  for (int base = 0; base < 64; base += 2) {
    KTILE(base,     0);
    KTILE(base + 1, 1);
  }
  KTILE(64, 0);

  // ---- epilogue: C/D layout col = lane&15, row = (lane>>4)*4 + e ----
  const int colb = bn * 256 + wn * 64 + lr;
  const int rowb = bm * 256 + wm * 128 + lg * 4;
#pragma unroll
  for (int j = 0; j < 4; ++j) {
    const int gc = colb + j * 16;
    const float bv = bias[gc];
#pragma unroll
    for (int q = 0; q < 4; ++q)
#pragma unroll
      for (int i = 0; i < 2; ++i) {
        const int gr = rowb + q * 32 + i * 16;
#pragma unroll
        for (int e = 0; e < 4; ++e)
          C[(size_t)(gr + e) * N_DIM + gc] = acc[q * 2 + i][j][e] + bv;
      }
  }
#undef STAGE_A
#undef STAGE_B
#undef LOAD_A
#undef LOAD_BN
#undef MFMA_Q
#undef KTILE
}

// ---------------------------------------------------------------------------
extern "C" void kernel_launch(void* const* d_in, const int* in_sizes, int n_in,
                              void* d_out, int out_size, void* d_ws, size_t ws_size,
                              hipStream_t stream) {
  const float* x         = (const float*)d_in[0];
  const float* w_res     = (const float*)d_in[1];
  const float* lora_down = (const float*)d_in[2];
  const float* lora_up   = (const float*)d_in[3];
  const float* smooth    = (const float*)d_in[4];
  const float* b         = (const float*)d_in[5];
  float* out = (float*)d_out;

  // workspace: Ap [M][KPAD] bf16 (68.2 MB), Bp [N][KPAD] bf16 (34.1 MB),
  // ldT [R][K] bf16 (256 KB)
  bf16_t* Ap  = (bf16_t*)d_ws;
  bf16_t* Bp  = Ap + (size_t)M_DIM * KPAD;
  bf16_t* ldT = Bp + (size_t)N_DIM * KPAD;

  // allow 128 KiB dynamic LDS (idempotent, host-side, capture-safe)
  hipFuncSetAttribute((const void*)gemm_kernel,
                      hipFuncAttributeMaxDynamicSharedMemorySize, 131072);

  prep_kernel<<<M_DIM + N_DIM + K_DIM / 256, 256, 0, stream>>>(
      x, smooth, w_res, lora_up, lora_down, Ap, Bp, ldT);
  lora_mfma_kernel<<<M_DIM / 32, 256, 0, stream>>>(x, smooth, ldT, Ap);
  gemm_kernel<<<(M_DIM / 256) * (N_DIM / 256), 512, 131072, stream>>>(Ap, Bp, b, out);
}

// Round 14
// 302.807 us; speedup vs baseline: 6.9241x; 1.1813x over previous
//
#include <hip/hip_runtime.h>
#include <hip/hip_bf16.h>
#include <stdint.h>

#define M_DIM 8192
#define N_DIM 4096
#define K_DIM 4096
#define R_DIM 32
#define KPAD  4160   // 4096 quant cols + 32 lora cols + 32 zero pad = 65 * 64
#define NT    65     // K-tiles of 64
#define QMAXF 7.0f

using bf16_t = __hip_bfloat16;
typedef __attribute__((ext_vector_type(4))) float f32x4;
typedef __attribute__((ext_vector_type(8))) short bf16x8;

// ---------------------------------------------------------------------------
// async global->LDS 16B stage (LDS dest = wave-uniform base + lane*16)
// ---------------------------------------------------------------------------
__device__ __forceinline__ void stage16(const void* g, void* l) {
#if defined(__has_builtin) && __has_builtin(__builtin_amdgcn_global_load_lds)
  __builtin_amdgcn_global_load_lds(
      (const __attribute__((address_space(1))) unsigned int*)g,
      (__attribute__((address_space(3))) unsigned int*)l, 16, 0, 0);
#else
  *(uint4*)l = *(const uint4*)g;
#endif
}

// ---------------------------------------------------------------------------
// prep_w kernel: block-range dispatch.
//   blocks [0, 4096)    : quant_w -> Bp cols 0..4095, lora_up 4096..4127, pad
//   blocks [4096, 4112) : ldT     (lora_down [K][R] -> bf16 ldT [R][K])
// ---------------------------------------------------------------------------
__global__ __launch_bounds__(256) void prep_w_kernel(
    const float* __restrict__ w, const float* __restrict__ lora_up,
    const float* __restrict__ ld,
    bf16_t* __restrict__ Bp, bf16_t* __restrict__ ldT) {
  const int bid = blockIdx.x;
  const int tid = threadIdx.x;

  if (bid < N_DIM) {                       // ---- quant_w ----
    const int row = bid;
    const int k0  = tid * 16;
    const float* wr = w + (size_t)row * K_DIM + k0;

    float v[16];
#pragma unroll
    for (int i = 0; i < 4; ++i) {
      float4 wv = *(const float4*)(wr + i * 4);
      v[i*4+0] = wv.x; v[i*4+1] = wv.y; v[i*4+2] = wv.z; v[i*4+3] = wv.w;
    }
    float am = 0.f;
#pragma unroll
    for (int i = 0; i < 16; ++i) am = fmaxf(am, fabsf(v[i]));
    am = fmaxf(am, __shfl_xor(am, 1));
    am = fmaxf(am, __shfl_xor(am, 2));
    const float scale = fmaxf(am / QMAXF, 1e-8f);

    alignas(16) bf16_t o[16];
#pragma unroll
    for (int i = 0; i < 16; ++i) {
      float q = rintf(v[i] / scale);       // IEEE div + round-half-even = jnp
      q = fminf(fmaxf(q, -8.f), 7.f);
      o[i] = __float2bfloat16(q * scale);
    }
    bf16_t* dst = Bp + (size_t)row * KPAD + k0;
    ((uint4*)dst)[0] = ((uint4*)o)[0];
    ((uint4*)dst)[1] = ((uint4*)o)[1];
    if (tid < 32) {
      Bp[(size_t)row * KPAD + 4096 + tid] = __float2bfloat16(lora_up[row * R_DIM + tid]);
    } else if (tid < 64) {
      Bp[(size_t)row * KPAD + 4096 + tid] = __float2bfloat16(0.f);
    }

  } else {                                 // ---- ldT ----
    const int k = (bid - N_DIM) * 256 + tid;
    float v[R_DIM];
#pragma unroll
    for (int i = 0; i < R_DIM / 4; ++i) {
      float4 a = *(const float4*)(ld + (size_t)k * R_DIM + i * 4);
      v[i*4+0] = a.x; v[i*4+1] = a.y; v[i*4+2] = a.z; v[i*4+3] = a.w;
    }
#pragma unroll
    for (int r = 0; r < R_DIM; ++r)
      ldT[(size_t)r * K_DIM + k] = __float2bfloat16(v[r]);
  }
}

// ---------------------------------------------------------------------------
// fused_x kernel: SINGLE pass over x does BOTH
//   (a) smooth + per-group(64) int4 fake-quant -> Ap cols 0..4095 (+ zero pad)
//   (b) t = xs @ lora_down (both 16-col halves) -> Ap cols 4096..4127
// Block = 16 x-rows, 256 threads; wave w owns k-quarter [w*1024,(w+1)*1024)
// (group-64 boundaries align).  Lane l: row = l&15, k-granule = l>>4.
// Per step-pair (64 k = one quant group): 16 smoothed f32 in regs ->
// 4 MFMA (2 col-tiles x 2 k-steps) + absmax shfl_xor(16,32) over the 4
// row-partner lanes -> quantize -> 2x16B stores (64B/row coalesced).
// Cross-wave t reduction via LDS (waves 1-3 write partials, wave 0 sums).
// x read ONCE (was 3x across prep+lora = 402 MB -> 134 MB).
// ---------------------------------------------------------------------------
__global__ __launch_bounds__(256) void fused_x_kernel(
    const float* __restrict__ x, const float* __restrict__ smooth,
    const bf16_t* __restrict__ ldT, bf16_t* __restrict__ Ap) {
  __shared__ float tpart[3][16][32];

  const int tid  = threadIdx.x;
  const int w    = tid >> 6;      // k-quarter 0..3
  const int lane = tid & 63;
  const int r    = lane & 15;     // x row within block
  const int kg   = lane >> 4;     // k-granule 0..3
  const int m0   = blockIdx.x * 16;
  const int mrow = m0 + r;

  const float*  xr  = x + (size_t)mrow * K_DIM;
  const bf16_t* br0 = ldT + (size_t)r * K_DIM;          // col tile 0: n = r
  const bf16_t* br1 = ldT + (size_t)(16 + r) * K_DIM;   // col tile 1: n = 16+r

  f32x4 acc0 = {0.f, 0.f, 0.f, 0.f};
  f32x4 acc1 = {0.f, 0.f, 0.f, 0.f};
  const int kbase = w * 1024;

  for (int s = 0; s < 32; s += 2) {
    const int ke = kbase + s * 32 + kg * 8;   // even step, this lane's 8 elems
    const int ko = ke + 32;                   // odd step

    float v[16];
    union { bf16_t h[8]; bf16x8 vv; } aue, auo;
    {
      float4 x0 = *(const float4*)(xr + ke);
      float4 x1 = *(const float4*)(xr + ke + 4);
      float4 s0 = *(const float4*)(smooth + ke);
      float4 s1 = *(const float4*)(smooth + ke + 4);
      v[0] = x0.x * s0.x; v[1] = x0.y * s0.y; v[2] = x0.z * s0.z; v[3] = x0.w * s0.w;
      v[4] = x1.x * s1.x; v[5] = x1.y * s1.y; v[6] = x1.z * s1.z; v[7] = x1.w * s1.w;
    }
    {
      float4 x0 = *(const float4*)(xr + ko);
      float4 x1 = *(const float4*)(xr + ko + 4);
      float4 s0 = *(const float4*)(smooth + ko);
      float4 s1 = *(const float4*)(smooth + ko + 4);
      v[8]  = x0.x * s0.x; v[9]  = x0.y * s0.y; v[10] = x0.z * s0.z; v[11] = x0.w * s0.w;
      v[12] = x1.x * s1.x; v[13] = x1.y * s1.y; v[14] = x1.z * s1.z; v[15] = x1.w * s1.w;
    }
#pragma unroll
    for (int i = 0; i < 8; ++i) {
      aue.h[i] = __float2bfloat16(v[i]);
      auo.h[i] = __float2bfloat16(v[8 + i]);
    }

    // lora MFMA (xs in bf16, both col tiles, both k-steps)
    acc0 = __builtin_amdgcn_mfma_f32_16x16x32_bf16(aue.vv, *(const bf16x8*)(br0 + ke), acc0, 0, 0, 0);
    acc1 = __builtin_amdgcn_mfma_f32_16x16x32_bf16(aue.vv, *(const bf16x8*)(br1 + ke), acc1, 0, 0, 0);
    acc0 = __builtin_amdgcn_mfma_f32_16x16x32_bf16(auo.vv, *(const bf16x8*)(br0 + ko), acc0, 0, 0, 0);
    acc1 = __builtin_amdgcn_mfma_f32_16x16x32_bf16(auo.vv, *(const bf16x8*)(br1 + ko), acc1, 0, 0, 0);

    // quantization of this group (64 k = lanes {r,r+16,r+32,r+48} x 16 elems)
    float am = 0.f;
#pragma unroll
    for (int i = 0; i < 16; ++i) am = fmaxf(am, fabsf(v[i]));
    am = fmaxf(am, __shfl_xor(am, 16));
    am = fmaxf(am, __shfl_xor(am, 32));
    const float scale = fmaxf(am / QMAXF, 1e-8f);

    alignas(16) bf16_t o[16];
#pragma unroll
    for (int i = 0; i < 16; ++i) {
      float q = rintf(v[i] / scale);       // IEEE div + round-half-even = jnp
      q = fminf(fmaxf(q, -8.f), 7.f);
      o[i] = __float2bfloat16(q * scale);
    }
    *(uint4*)(Ap + (size_t)mrow * KPAD + ke) = ((const uint4*)o)[0];
    *(uint4*)(Ap + (size_t)mrow * KPAD + ko) = ((const uint4*)o)[1];
  }

  // ---- cross-wave t reduction: C/D layout col=lane&15, row=(lane>>4)*4+q ----
  if (w != 0) {
#pragma unroll
    for (int q = 0; q < 4; ++q) {
      tpart[w - 1][kg * 4 + q][r]      = acc0[q];
      tpart[w - 1][kg * 4 + q][16 + r] = acc1[q];
    }
  }
  __syncthreads();
  if (w == 0) {
#pragma unroll
    for (int q = 0; q < 4; ++q) {
      const int orow = m0 + kg * 4 + q;
      float s0 = acc0[q], s1 = acc1[q];
#pragma unroll
      for (int j = 0; j < 3; ++j) {
        s0 += tpart[j][kg * 4 + q][r];
        s1 += tpart[j][kg * 4 + q][16 + r];
      }
      Ap[(size_t)orow * KPAD + 4096 + r]      = __float2bfloat16(s0);
      Ap[(size_t)orow * KPAD + 4096 + 16 + r] = __float2bfloat16(s1);
    }
    // zero pad cols 4128..4159
    alignas(16) bf16_t z[8] = {};
    *(uint4*)(Ap + (size_t)mrow * KPAD + 4128 + kg * 8) = *(const uint4*)z;
  }
}

// ---------------------------------------------------------------------------
// 256x256x64 8-phase GEMM (session champion, 255 us / 1094 TF measured):
// A-fragments pipelined one phase ahead (aA/aB ping-pong), B-fragments
// single-set re-read once per ktile at P4's tail after the MFMA cluster
// (WAR-safe via in-order issue; LDS data valid per the vmcnt(6) ring).
// Stage ring: P1: A2(u+1)->buf^1 | P2: B1(u+2)->buf | P3: B2(u+2)->buf |
//   P4: A1(u+2)->buf + vmcnt(6)  (tail: vmcnt(0)).  vmcnt(6) at P4(u)
//   retires exactly all of ktile u+1 (queue 6+2+6=14 -> retire 8).
// A quadrant-major LDS (lds_row = q*64 + wm*32 + r).  Swizzle: 16B granule
// ^= (row&7) on stage-source and ds_read (measured 0 conflicts).
// ---------------------------------------------------------------------------
__global__ __launch_bounds__(512, 2) void gemm_kernel(
    const bf16_t* __restrict__ A, const bf16_t* __restrict__ B,
    const float* __restrict__ bias, float* __restrict__ C) {
  extern __shared__ __align__(16) bf16_t lds[];   // 65536 elems = 128 KiB

  // XCD-aware swizzle: nwg = 512, divisible by 8
  const int wg  = blockIdx.x;
  const int swz = (wg & 7) * 64 + (wg >> 3);
  const int bn  = swz & 15;    // 0..15
  const int bm  = swz >> 4;    // 0..31

  const int tid  = threadIdx.x;
  const int lane = tid & 63;
  const int wid  = tid >> 6;     // 0..7
  const int wm   = wid >> 2;     // 0..1
  const int wn   = wid & 3;      // 0..3

  const int lr = lane & 15;      // frag row within 16
  const int lg = lane >> 4;      // k-granule subindex 0..3
  const int l7 = lane & 7;
  const int gk0 = ((0 + lg) ^ l7) * 8;   // swizzled elem offset, k-half 0
  const int gk1 = ((4 + lg) ^ l7) * 8;   // k-half 1

  // staging geometry
  const int sr   = tid >> 3;                 // 0..63
  const int sl   = tid & 7;                  // granule slot
  const int gcol = (sl ^ (sr & 7)) * 8;      // inverse-swizzled source col
  const bf16_t* Abase = A + (size_t)(bm * 256 + ((sr >> 5) & 1) * 128 + (sr & 31)) * KPAD + gcol;
  const bf16_t* Bbase = B + (size_t)(bn * 256 + sr) * KPAD + gcol;
  bf16_t* ldsb = lds;

#define STAGE_A(buf, h, kt) do {                                               \
    stage16(Abase + (size_t)((h) * 2 + 0) * 32 * KPAD + (kt) * 64,             \
            ldsb + (buf) * 32768 + (h) * 8192 + 0 * 4096 + tid * 8);           \
    stage16(Abase + (size_t)((h) * 2 + 1) * 32 * KPAD + (kt) * 64,             \
            ldsb + (buf) * 32768 + (h) * 8192 + 1 * 4096 + tid * 8);           \
  } while (0)
#define STAGE_B(buf, h, kt) do {                                               \
    stage16(Bbase + (size_t)((h) * 128 + 0) * KPAD + (kt) * 64,                \
            ldsb + (buf) * 32768 + 16384 + (h) * 8192 + 0 * 4096 + tid * 8);   \
    stage16(Bbase + (size_t)((h) * 128 + 64) * KPAD + (kt) * 64,               \
            ldsb + (buf) * 32768 + 16384 + (h) * 8192 + 1 * 4096 + tid * 8);   \
  } while (0)

  f32x4  acc[8][4] = {};
  bf16x8 aA[2][2];   // A-frag ping (quadrants 0,2)
  bf16x8 aB[2][2];   // A-frag pong (quadrants 1,3)
  bf16x8 bF[4][2];   // B-frags, one set, reloaded per ktile

#define LOAD_A(DST, q, cb) do {                                                \
    const bf16_t* pa_ = ldsb + (cb) * 32768 + ((q) * 64 + wm * 32 + lr) * 64;  \
    DST[0][0] = *(const bf16x8*)(pa_ + gk0);                                   \
    DST[0][1] = *(const bf16x8*)(pa_ + gk1);                                   \
    DST[1][0] = *(const bf16x8*)(pa_ + 1024 + gk0);                            \
    DST[1][1] = *(const bf16x8*)(pa_ + 1024 + gk1);                            \
  } while (0)
#define LOAD_BN(nbuf) do {                                                     \
    _Pragma("unroll")                                                          \
    for (int j = 0; j < 4; ++j) {                                              \
      const bf16_t* pb_ = ldsb + (nbuf) * 32768 + 16384 + (wn * 64 + j * 16 + lr) * 64; \
      bF[j][0] = *(const bf16x8*)(pb_ + gk0);                                  \
      bF[j][1] = *(const bf16x8*)(pb_ + gk1);                                  \
    }                                                                          \
  } while (0)
#define MFMA_Q(q, AARR) do {                                                   \
    _Pragma("unroll")                                                          \
    for (int i = 0; i < 2; ++i)                                                \
      _Pragma("unroll")                                                        \
      for (int j = 0; j < 4; ++j) {                                            \
        acc[(q)*2+i][j] = __builtin_amdgcn_mfma_f32_16x16x32_bf16(             \
            AARR[i][0], bF[j][0], acc[(q)*2+i][j], 0, 0, 0);                   \
        acc[(q)*2+i][j] = __builtin_amdgcn_mfma_f32_16x16x32_bf16(             \
            AARR[i][1], bF[j][1], acc[(q)*2+i][j], 0, 0, 0);                   \
      }                                                                        \
  } while (0)

#define KTILE(u, cur) do {                                                     \
    /* ---- P1 ---- */                                                         \
    if ((u) + 1 < NT) STAGE_A((cur) ^ 1, 1, (u) + 1);                          \
    __builtin_amdgcn_s_barrier();                                              \
    asm volatile("s_waitcnt lgkmcnt(0)" ::: "memory");                         \
    __builtin_amdgcn_sched_barrier(0);                                         \
    LOAD_A(aB, 1, cur);                                                        \
    __builtin_amdgcn_sched_barrier(0);                                         \
    __builtin_amdgcn_s_setprio(1);                                             \
    MFMA_Q(0, aA);                                                             \
    __builtin_amdgcn_s_setprio(0);                                             \
    __builtin_amdgcn_s_barrier();                                              \
    /* ---- P2 ---- */                                                         \
    if ((u) + 2 < NT) STAGE_B(cur, 0, (u) + 2);                                \
    __builtin_amdgcn_s_barrier();                                              \
    asm volatile("s_waitcnt lgkmcnt(0)" ::: "memory");                         \
    __builtin_amdgcn_sched_barrier(0);                                         \
    LOAD_A(aA, 2, cur);                                                        \
    __builtin_amdgcn_sched_barrier(0);                                         \
    __builtin_amdgcn_s_setprio(1);                                             \
    MFMA_Q(1, aB);                                                             \
    __builtin_amdgcn_s_setprio(0);                                             \
    __builtin_amdgcn_s_barrier();                                              \
    /* ---- P3 ---- */                                                         \
    if ((u) + 2 < NT) STAGE_B(cur, 1, (u) + 2);                                \
    __builtin_amdgcn_s_barrier();                                              \
    asm volatile("s_waitcnt lgkmcnt(0)" ::: "memory");                         \
    __builtin_amdgcn_sched_barrier(0);                                         \
    LOAD_A(aB, 3, cur);                                                        \
    __builtin_amdgcn_sched_barrier(0);                                         \
    __builtin_amdgcn_s_setprio(1);                                             \
    MFMA_Q(2, aA);                                                             \
    __builtin_amdgcn_s_setprio(0);                                             \
    __builtin_amdgcn_s_barrier();                                              \
    /* ---- P4 ---- */                                                         \
    if ((u) + 2 < NT) {                                                        \
      STAGE_A(cur, 0, (u) + 2);                                                \
      asm volatile("s_waitcnt vmcnt(6)" ::: "memory");                         \
    } else {                                                                   \
      asm volatile("s_waitcnt vmcnt(0)" ::: "memory");                         \
    }                                                                          \
    __builtin_amdgcn_s_barrier();                                              \
    asm volatile("s_waitcnt lgkmcnt(0)" ::: "memory");                         \
    __builtin_amdgcn_sched_barrier(0);                                         \
    if ((u) + 1 < NT) LOAD_A(aA, 0, (cur) ^ 1);                                \
    __builtin_amdgcn_sched_barrier(0);                                         \
    __builtin_amdgcn_s_setprio(1);                                             \
    MFMA_Q(3, aB);                                                             \
    __builtin_amdgcn_s_setprio(0);                                             \
    __builtin_amdgcn_sched_barrier(0);                                         \
    if ((u) + 1 < NT) LOAD_BN((cur) ^ 1);                                      \
    __builtin_amdgcn_s_barrier();                                              \
  } while (0)

  // ---- prologue: stage ktile0 fully + ktile1's B1,B2,A1; wait ktile0;
  //      preload B(0) and A-q0(0) fragment registers ----
  STAGE_B(0, 0, 0); STAGE_B(0, 1, 0); STAGE_A(0, 0, 0); STAGE_A(0, 1, 0);
  STAGE_B(1, 0, 1); STAGE_B(1, 1, 1); STAGE_A(1, 0, 1);
  asm volatile("s_waitcnt vmcnt(6)" ::: "memory");
  __builtin_amdgcn_s_barrier();
  LOAD_BN(0);
  LOAD_A(aA, 0, 0);

  for (int base = 0; base < 64; base += 2) {
    KTILE(base,     0);
    KTILE(base + 1, 1);
  }
  KTILE(64, 0);

  // ---- epilogue: C/D layout col = lane&15, row = (lane>>4)*4 + e ----
  const int colb = bn * 256 + wn * 64 + lr;
  const int rowb = bm * 256 + wm * 128 + lg * 4;
#pragma unroll
  for (int j = 0; j < 4; ++j) {
    const int gc = colb + j * 16;
    const float bv = bias[gc];
#pragma unroll
    for (int q = 0; q < 4; ++q)
#pragma unroll
      for (int i = 0; i < 2; ++i) {
        const int gr = rowb + q * 32 + i * 16;
#pragma unroll
        for (int e = 0; e < 4; ++e)
          C[(size_t)(gr + e) * N_DIM + gc] = acc[q * 2 + i][j][e] + bv;
      }
  }
#undef STAGE_A
#undef STAGE_B
#undef LOAD_A
#undef LOAD_BN
#undef MFMA_Q
#undef KTILE
}

// ---------------------------------------------------------------------------
extern "C" void kernel_launch(void* const* d_in, const int* in_sizes, int n_in,
                              void* d_out, int out_size, void* d_ws, size_t ws_size,
                              hipStream_t stream) {
  const float* x         = (const float*)d_in[0];
  const float* w_res     = (const float*)d_in[1];
  const float* lora_down = (const float*)d_in[2];
  const float* lora_up   = (const float*)d_in[3];
  const float* smooth    = (const float*)d_in[4];
  const float* b         = (const float*)d_in[5];
  float* out = (float*)d_out;

  // workspace: Ap [M][KPAD] bf16 (68.2 MB), Bp [N][KPAD] bf16 (34.1 MB),
  // ldT [R][K] bf16 (256 KB)
  bf16_t* Ap  = (bf16_t*)d_ws;
  bf16_t* Bp  = Ap + (size_t)M_DIM * KPAD;
  bf16_t* ldT = Bp + (size_t)N_DIM * KPAD;

  // allow 128 KiB dynamic LDS (idempotent, host-side, capture-safe)
  hipFuncSetAttribute((const void*)gemm_kernel,
                      hipFuncAttributeMaxDynamicSharedMemorySize, 131072);

  prep_w_kernel<<<N_DIM + K_DIM / 256, 256, 0, stream>>>(
      w_res, lora_up, lora_down, Bp, ldT);
  fused_x_kernel<<<M_DIM / 16, 256, 0, stream>>>(x, smooth, ldT, Ap);
  gemm_kernel<<<(M_DIM / 256) * (N_DIM / 256), 512, 131072, stream>>>(Ap, Bp, b, out);
}

// Round 15
// 300.659 us; speedup vs baseline: 6.9736x; 1.0071x over previous
//
#include <hip/hip_runtime.h>
#include <hip/hip_bf16.h>
#include <stdint.h>

#define M_DIM 8192
#define N_DIM 4096
#define K_DIM 4096
#define R_DIM 32
#define KPAD  4160   // 4096 quant cols + 32 lora cols + 32 zero pad = 65 * 64
#define NT    65     // K-tiles of 64
#define QMAXF 7.0f

using bf16_t = __hip_bfloat16;
typedef __attribute__((ext_vector_type(4))) float f32x4;
typedef __attribute__((ext_vector_type(8))) short bf16x8;

// ---------------------------------------------------------------------------
// async global->LDS 16B stage (LDS dest = wave-uniform base + lane*16)
// ---------------------------------------------------------------------------
__device__ __forceinline__ void stage16(const void* g, void* l) {
#if defined(__has_builtin) && __has_builtin(__builtin_amdgcn_global_load_lds)
  __builtin_amdgcn_global_load_lds(
      (const __attribute__((address_space(1))) unsigned int*)g,
      (__attribute__((address_space(3))) unsigned int*)l, 16, 0, 0);
#else
  *(uint4*)l = *(const uint4*)g;
#endif
}

// ---------------------------------------------------------------------------
// prep_w kernel: block-range dispatch.
//   blocks [0, 4096)    : quant_w -> Bp cols 0..4095, lora_up 4096..4127, pad
//   blocks [4096, 4112) : ldT     (lora_down [K][R] -> bf16 ldT [R][K])
// ---------------------------------------------------------------------------
__global__ __launch_bounds__(256) void prep_w_kernel(
    const float* __restrict__ w, const float* __restrict__ lora_up,
    const float* __restrict__ ld,
    bf16_t* __restrict__ Bp, bf16_t* __restrict__ ldT) {
  const int bid = blockIdx.x;
  const int tid = threadIdx.x;

  if (bid < N_DIM) {                       // ---- quant_w ----
    const int row = bid;
    const int k0  = tid * 16;
    const float* wr = w + (size_t)row * K_DIM + k0;

    float v[16];
#pragma unroll
    for (int i = 0; i < 4; ++i) {
      float4 wv = *(const float4*)(wr + i * 4);
      v[i*4+0] = wv.x; v[i*4+1] = wv.y; v[i*4+2] = wv.z; v[i*4+3] = wv.w;
    }
    float am = 0.f;
#pragma unroll
    for (int i = 0; i < 16; ++i) am = fmaxf(am, fabsf(v[i]));
    am = fmaxf(am, __shfl_xor(am, 1));
    am = fmaxf(am, __shfl_xor(am, 2));
    const float scale = fmaxf(am / QMAXF, 1e-8f);

    alignas(16) bf16_t o[16];
#pragma unroll
    for (int i = 0; i < 16; ++i) {
      float q = rintf(v[i] / scale);       // IEEE div + round-half-even = jnp
      q = fminf(fmaxf(q, -8.f), 7.f);
      o[i] = __float2bfloat16(q * scale);
    }
    bf16_t* dst = Bp + (size_t)row * KPAD + k0;
    ((uint4*)dst)[0] = ((uint4*)o)[0];
    ((uint4*)dst)[1] = ((uint4*)o)[1];
    if (tid < 32) {
      Bp[(size_t)row * KPAD + 4096 + tid] = __float2bfloat16(lora_up[row * R_DIM + tid]);
    } else if (tid < 64) {
      Bp[(size_t)row * KPAD + 4096 + tid] = __float2bfloat16(0.f);
    }

  } else {                                 // ---- ldT ----
    const int k = (bid - N_DIM) * 256 + tid;
    float v[R_DIM];
#pragma unroll
    for (int i = 0; i < R_DIM / 4; ++i) {
      float4 a = *(const float4*)(ld + (size_t)k * R_DIM + i * 4);
      v[i*4+0] = a.x; v[i*4+1] = a.y; v[i*4+2] = a.z; v[i*4+3] = a.w;
    }
#pragma unroll
    for (int r = 0; r < R_DIM; ++r)
      ldT[(size_t)r * K_DIM + k] = __float2bfloat16(v[r]);
  }
}

// ---------------------------------------------------------------------------
// fused_x kernel: SINGLE pass over x does BOTH
//   (a) smooth + per-group(64) int4 fake-quant -> Ap cols 0..4095 (+ zero pad)
//   (b) t = xs @ lora_down (both 16-col halves) -> Ap cols 4096..4127
// Block = 16 x-rows, 256 threads; wave w owns k-quarter [w*1024,(w+1)*1024).
// Measured (round 14): ~5.3 TB/s, near HBM ceiling.
// ---------------------------------------------------------------------------
__global__ __launch_bounds__(256) void fused_x_kernel(
    const float* __restrict__ x, const float* __restrict__ smooth,
    const bf16_t* __restrict__ ldT, bf16_t* __restrict__ Ap) {
  __shared__ float tpart[3][16][32];

  const int tid  = threadIdx.x;
  const int w    = tid >> 6;      // k-quarter 0..3
  const int lane = tid & 63;
  const int r    = lane & 15;     // x row within block
  const int kg   = lane >> 4;     // k-granule 0..3
  const int m0   = blockIdx.x * 16;
  const int mrow = m0 + r;

  const float*  xr  = x + (size_t)mrow * K_DIM;
  const bf16_t* br0 = ldT + (size_t)r * K_DIM;          // col tile 0: n = r
  const bf16_t* br1 = ldT + (size_t)(16 + r) * K_DIM;   // col tile 1: n = 16+r

  f32x4 acc0 = {0.f, 0.f, 0.f, 0.f};
  f32x4 acc1 = {0.f, 0.f, 0.f, 0.f};
  const int kbase = w * 1024;

  for (int s = 0; s < 32; s += 2) {
    const int ke = kbase + s * 32 + kg * 8;   // even step, this lane's 8 elems
    const int ko = ke + 32;                   // odd step

    float v[16];
    union { bf16_t h[8]; bf16x8 vv; } aue, auo;
    {
      float4 x0 = *(const float4*)(xr + ke);
      float4 x1 = *(const float4*)(xr + ke + 4);
      float4 s0 = *(const float4*)(smooth + ke);
      float4 s1 = *(const float4*)(smooth + ke + 4);
      v[0] = x0.x * s0.x; v[1] = x0.y * s0.y; v[2] = x0.z * s0.z; v[3] = x0.w * s0.w;
      v[4] = x1.x * s1.x; v[5] = x1.y * s1.y; v[6] = x1.z * s1.z; v[7] = x1.w * s1.w;
    }
    {
      float4 x0 = *(const float4*)(xr + ko);
      float4 x1 = *(const float4*)(xr + ko + 4);
      float4 s0 = *(const float4*)(smooth + ko);
      float4 s1 = *(const float4*)(smooth + ko + 4);
      v[8]  = x0.x * s0.x; v[9]  = x0.y * s0.y; v[10] = x0.z * s0.z; v[11] = x0.w * s0.w;
      v[12] = x1.x * s1.x; v[13] = x1.y * s1.y; v[14] = x1.z * s1.z; v[15] = x1.w * s1.w;
    }
#pragma unroll
    for (int i = 0; i < 8; ++i) {
      aue.h[i] = __float2bfloat16(v[i]);
      auo.h[i] = __float2bfloat16(v[8 + i]);
    }

    // lora MFMA (xs in bf16, both col tiles, both k-steps)
    acc0 = __builtin_amdgcn_mfma_f32_16x16x32_bf16(aue.vv, *(const bf16x8*)(br0 + ke), acc0, 0, 0, 0);
    acc1 = __builtin_amdgcn_mfma_f32_16x16x32_bf16(aue.vv, *(const bf16x8*)(br1 + ke), acc1, 0, 0, 0);
    acc0 = __builtin_amdgcn_mfma_f32_16x16x32_bf16(auo.vv, *(const bf16x8*)(br0 + ko), acc0, 0, 0, 0);
    acc1 = __builtin_amdgcn_mfma_f32_16x16x32_bf16(auo.vv, *(const bf16x8*)(br1 + ko), acc1, 0, 0, 0);

    // quantization of this group (64 k = lanes {r,r+16,r+32,r+48} x 16 elems)
    float am = 0.f;
#pragma unroll
    for (int i = 0; i < 16; ++i) am = fmaxf(am, fabsf(v[i]));
    am = fmaxf(am, __shfl_xor(am, 16));
    am = fmaxf(am, __shfl_xor(am, 32));
    const float scale = fmaxf(am / QMAXF, 1e-8f);

    alignas(16) bf16_t o[16];
#pragma unroll
    for (int i = 0; i < 16; ++i) {
      float q = rintf(v[i] / scale);       // IEEE div + round-half-even = jnp
      q = fminf(fmaxf(q, -8.f), 7.f);
      o[i] = __float2bfloat16(q * scale);
    }
    *(uint4*)(Ap + (size_t)mrow * KPAD + ke) = ((const uint4*)o)[0];
    *(uint4*)(Ap + (size_t)mrow * KPAD + ko) = ((const uint4*)o)[1];
  }

  // ---- cross-wave t reduction: C/D layout col=lane&15, row=(lane>>4)*4+q ----
  if (w != 0) {
#pragma unroll
    for (int q = 0; q < 4; ++q) {
      tpart[w - 1][kg * 4 + q][r]      = acc0[q];
      tpart[w - 1][kg * 4 + q][16 + r] = acc1[q];
    }
  }
  __syncthreads();
  if (w == 0) {
#pragma unroll
    for (int q = 0; q < 4; ++q) {
      const int orow = m0 + kg * 4 + q;
      float s0 = acc0[q], s1 = acc1[q];
#pragma unroll
      for (int j = 0; j < 3; ++j) {
        s0 += tpart[j][kg * 4 + q][r];
        s1 += tpart[j][kg * 4 + q][16 + r];
      }
      Ap[(size_t)orow * KPAD + 4096 + r]      = __float2bfloat16(s0);
      Ap[(size_t)orow * KPAD + 4096 + 16 + r] = __float2bfloat16(s1);
    }
    // zero pad cols 4128..4159
    alignas(16) bf16_t z[8] = {};
    *(uint4*)(Ap + (size_t)mrow * KPAD + 4128 + kg * 8) = *(const uint4*)z;
  }
}

// ---------------------------------------------------------------------------
// 256x256x64 8-phase GEMM, 5 barriers/ktile (was 8).  Round-15 change:
// removed the three redundant "phase-open" barriers in P1/P2/P3 heads.
// Hazard proof: every stage's victim LDS region has its last ds_read
// drained at a lgkmcnt(0) that precedes the PREVIOUS phase-close barrier,
// which in turn precedes the stage's issue:
//   A2(u+1)@Ph1: victims' reads drained pre-bar4b(u-1);
//   B1/B2(u+2)@Ph2/Ph3: LOAD_BN(cur) drained at Ph1(u) lgkm0, pre-bar1;
//   A1(u+2)@Ph4: q0 drained pre-bar1, q1 drained at Ph2 lgkm0 pre-bar2.
// P4's vmcnt(6) -> barrier pair is MANDATORY (vmcnt is per-wave; LDS
// staging is cross-wave) and is kept.  vmcnt accounting unchanged:
// at P4(u) queue = 14, retire 8 = exactly all of ktile u+1.
// A quadrant-major LDS (lds_row = q*64 + wm*32 + r).  Swizzle: 16B granule
// ^= (row&7) on stage-source and ds_read (measured 0 conflicts).
// ---------------------------------------------------------------------------
__global__ __launch_bounds__(512, 2) void gemm_kernel(
    const bf16_t* __restrict__ A, const bf16_t* __restrict__ B,
    const float* __restrict__ bias, float* __restrict__ C) {
  extern __shared__ __align__(16) bf16_t lds[];   // 65536 elems = 128 KiB

  // XCD-aware swizzle: nwg = 512, divisible by 8
  const int wg  = blockIdx.x;
  const int swz = (wg & 7) * 64 + (wg >> 3);
  const int bn  = swz & 15;    // 0..15
  const int bm  = swz >> 4;    // 0..31

  const int tid  = threadIdx.x;
  const int lane = tid & 63;
  const int wid  = tid >> 6;     // 0..7
  const int wm   = wid >> 2;     // 0..1
  const int wn   = wid & 3;      // 0..3

  const int lr = lane & 15;      // frag row within 16
  const int lg = lane >> 4;      // k-granule subindex 0..3
  const int l7 = lane & 7;
  const int gk0 = ((0 + lg) ^ l7) * 8;   // swizzled elem offset, k-half 0
  const int gk1 = ((4 + lg) ^ l7) * 8;   // k-half 1

  // staging geometry
  const int sr   = tid >> 3;                 // 0..63
  const int sl   = tid & 7;                  // granule slot
  const int gcol = (sl ^ (sr & 7)) * 8;      // inverse-swizzled source col
  const bf16_t* Abase = A + (size_t)(bm * 256 + ((sr >> 5) & 1) * 128 + (sr & 31)) * KPAD + gcol;
  const bf16_t* Bbase = B + (size_t)(bn * 256 + sr) * KPAD + gcol;
  bf16_t* ldsb = lds;

#define STAGE_A(buf, h, kt) do {                                               \
    stage16(Abase + (size_t)((h) * 2 + 0) * 32 * KPAD + (kt) * 64,             \
            ldsb + (buf) * 32768 + (h) * 8192 + 0 * 4096 + tid * 8);           \
    stage16(Abase + (size_t)((h) * 2 + 1) * 32 * KPAD + (kt) * 64,             \
            ldsb + (buf) * 32768 + (h) * 8192 + 1 * 4096 + tid * 8);           \
  } while (0)
#define STAGE_B(buf, h, kt) do {                                               \
    stage16(Bbase + (size_t)((h) * 128 + 0) * KPAD + (kt) * 64,                \
            ldsb + (buf) * 32768 + 16384 + (h) * 8192 + 0 * 4096 + tid * 8);   \
    stage16(Bbase + (size_t)((h) * 128 + 64) * KPAD + (kt) * 64,               \
            ldsb + (buf) * 32768 + 16384 + (h) * 8192 + 1 * 4096 + tid * 8);   \
  } while (0)

  f32x4  acc[8][4] = {};
  bf16x8 aA[2][2];   // A-frag ping (quadrants 0,2)
  bf16x8 aB[2][2];   // A-frag pong (quadrants 1,3)
  bf16x8 bF[4][2];   // B-frags, one set, reloaded per ktile

#define LOAD_A(DST, q, cb) do {                                                \
    const bf16_t* pa_ = ldsb + (cb) * 32768 + ((q) * 64 + wm * 32 + lr) * 64;  \
    DST[0][0] = *(const bf16x8*)(pa_ + gk0);                                   \
    DST[0][1] = *(const bf16x8*)(pa_ + gk1);                                   \
    DST[1][0] = *(const bf16x8*)(pa_ + 1024 + gk0);                            \
    DST[1][1] = *(const bf16x8*)(pa_ + 1024 + gk1);                            \
  } while (0)
#define LOAD_BN(nbuf) do {                                                     \
    _Pragma("unroll")                                                          \
    for (int j = 0; j < 4; ++j) {                                              \
      const bf16_t* pb_ = ldsb + (nbuf) * 32768 + 16384 + (wn * 64 + j * 16 + lr) * 64; \
      bF[j][0] = *(const bf16x8*)(pb_ + gk0);                                  \
      bF[j][1] = *(const bf16x8*)(pb_ + gk1);                                  \
    }                                                                          \
  } while (0)
#define MFMA_Q(q, AARR) do {                                                   \
    _Pragma("unroll")                                                          \
    for (int i = 0; i < 2; ++i)                                                \
      _Pragma("unroll")                                                        \
      for (int j = 0; j < 4; ++j) {                                            \
        acc[(q)*2+i][j] = __builtin_amdgcn_mfma_f32_16x16x32_bf16(             \
            AARR[i][0], bF[j][0], acc[(q)*2+i][j], 0, 0, 0);                   \
        acc[(q)*2+i][j] = __builtin_amdgcn_mfma_f32_16x16x32_bf16(             \
            AARR[i][1], bF[j][1], acc[(q)*2+i][j], 0, 0, 0);                   \
      }                                                                        \
  } while (0)

#define KTILE(u, cur) do {                                                     \
    /* ---- Ph1: stage A2(u+1); drain P4-tail reads; MFMA q0 ---- */           \
    if ((u) + 1 < NT) STAGE_A((cur) ^ 1, 1, (u) + 1);                          \
    asm volatile("s_waitcnt lgkmcnt(0)" ::: "memory");                         \
    __builtin_amdgcn_sched_barrier(0);                                         \
    LOAD_A(aB, 1, cur);                                                        \
    __builtin_amdgcn_sched_barrier(0);                                         \
    __builtin_amdgcn_s_setprio(1);                                             \
    MFMA_Q(0, aA);                                                             \
    __builtin_amdgcn_s_setprio(0);                                             \
    __builtin_amdgcn_s_barrier();                     /* bar1 */               \
    /* ---- Ph2: stage B1(u+2); MFMA q1 ---- */                                \
    if ((u) + 2 < NT) STAGE_B(cur, 0, (u) + 2);                                \
    asm volatile("s_waitcnt lgkmcnt(0)" ::: "memory");                         \
    __builtin_amdgcn_sched_barrier(0);                                         \
    LOAD_A(aA, 2, cur);                                                        \
    __builtin_amdgcn_sched_barrier(0);                                         \
    __builtin_amdgcn_s_setprio(1);                                             \
    MFMA_Q(1, aB);                                                             \
    __builtin_amdgcn_s_setprio(0);                                             \
    __builtin_amdgcn_s_barrier();                     /* bar2 */               \
    /* ---- Ph3: stage B2(u+2); MFMA q2 ---- */                                \
    if ((u) + 2 < NT) STAGE_B(cur, 1, (u) + 2);                                \
    asm volatile("s_waitcnt lgkmcnt(0)" ::: "memory");                         \
    __builtin_amdgcn_sched_barrier(0);                                         \
    LOAD_A(aB, 3, cur);                                                        \
    __builtin_amdgcn_sched_barrier(0);                                         \
    __builtin_amdgcn_s_setprio(1);                                             \
    MFMA_Q(2, aA);                                                             \
    __builtin_amdgcn_s_setprio(0);                                             \
    __builtin_amdgcn_s_barrier();                     /* bar3 */               \
    /* ---- Ph4: stage A1(u+2); counted wait; MANDATORY barrier; MFMA q3 */    \
    if ((u) + 2 < NT) {                                                        \
      STAGE_A(cur, 0, (u) + 2);                                                \
      asm volatile("s_waitcnt vmcnt(6)" ::: "memory");                         \
    } else {                                                                   \
      asm volatile("s_waitcnt vmcnt(0)" ::: "memory");                         \
    }                                                                          \
    __builtin_amdgcn_s_barrier();                     /* bar4a (vmcnt) */      \
    asm volatile("s_waitcnt lgkmcnt(0)" ::: "memory");                         \
    __builtin_amdgcn_sched_barrier(0);                                         \
    if ((u) + 1 < NT) LOAD_A(aA, 0, (cur) ^ 1);                                \
    __builtin_amdgcn_sched_barrier(0);                                         \
    __builtin_amdgcn_s_setprio(1);                                             \
    MFMA_Q(3, aB);                                                             \
    __builtin_amdgcn_s_setprio(0);                                             \
    __builtin_amdgcn_sched_barrier(0);                                         \
    if ((u) + 1 < NT) LOAD_BN((cur) ^ 1);                                      \
    __builtin_amdgcn_s_barrier();                     /* bar4b */              \
  } while (0)

  // ---- prologue: stage ktile0 fully + ktile1's B1,B2,A1; wait ktile0;
  //      preload B(0) and A-q0(0) fragment registers ----
  STAGE_B(0, 0, 0); STAGE_B(0, 1, 0); STAGE_A(0, 0, 0); STAGE_A(0, 1, 0);
  STAGE_B(1, 0, 1); STAGE_B(1, 1, 1); STAGE_A(1, 0, 1);
  asm volatile("s_waitcnt vmcnt(6)" ::: "memory");
  __builtin_amdgcn_s_barrier();
  LOAD_BN(0);
  LOAD_A(aA, 0, 0);

  for (int base = 0; base < 64; base += 2) {
    KTILE(base,     0);
    KTILE(base + 1, 1);
  }
  KTILE(64, 0);

  // ---- epilogue: C/D layout col = lane&15, row = (lane>>4)*4 + e ----
  const int colb = bn * 256 + wn * 64 + lr;
  const int rowb = bm * 256 + wm * 128 + lg * 4;
#pragma unroll
  for (int j = 0; j < 4; ++j) {
    const int gc = colb + j * 16;
    const float bv = bias[gc];
#pragma unroll
    for (int q = 0; q < 4; ++q)
#pragma unroll
      for (int i = 0; i < 2; ++i) {
        const int gr = rowb + q * 32 + i * 16;
#pragma unroll
        for (int e = 0; e < 4; ++e)
          C[(size_t)(gr + e) * N_DIM + gc] = acc[q * 2 + i][j][e] + bv;
      }
  }
#undef STAGE_A
#undef STAGE_B
#undef LOAD_A
#undef LOAD_BN
#undef MFMA_Q
#undef KTILE
}

// ---------------------------------------------------------------------------
extern "C" void kernel_launch(void* const* d_in, const int* in_sizes, int n_in,
                              void* d_out, int out_size, void* d_ws, size_t ws_size,
                              hipStream_t stream) {
  const float* x         = (const float*)d_in[0];
  const float* w_res     = (const float*)d_in[1];
  const float* lora_down = (const float*)d_in[2];
  const float* lora_up   = (const float*)d_in[3];
  const float* smooth    = (const float*)d_in[4];
  const float* b         = (const float*)d_in[5];
  float* out = (float*)d_out;

  // workspace: Ap [M][KPAD] bf16 (68.2 MB), Bp [N][KPAD] bf16 (34.1 MB),
  // ldT [R][K] bf16 (256 KB)
  bf16_t* Ap  = (bf16_t*)d_ws;
  bf16_t* Bp  = Ap + (size_t)M_DIM * KPAD;
  bf16_t* ldT = Bp + (size_t)N_DIM * KPAD;

  // allow 128 KiB dynamic LDS (idempotent, host-side, capture-safe)
  hipFuncSetAttribute((const void*)gemm_kernel,
                      hipFuncAttributeMaxDynamicSharedMemorySize, 131072);

  prep_w_kernel<<<N_DIM + K_DIM / 256, 256, 0, stream>>>(
      w_res, lora_up, lora_down, Bp, ldT);
  fused_x_kernel<<<M_DIM / 16, 256, 0, stream>>>(x, smooth, ldT, Ap);
  gemm_kernel<<<(M_DIM / 256) * (N_DIM / 256), 512, 131072, stream>>>(Ap, Bp, b, out);
}

// Round 16
// 298.649 us; speedup vs baseline: 7.0205x; 1.0067x over previous
//
#include <hip/hip_runtime.h>
#include <hip/hip_bf16.h>
#include <stdint.h>

#define M_DIM 8192
#define N_DIM 4096
#define K_DIM 4096
#define R_DIM 32
#define KPAD  4160   // 4096 quant cols + 32 lora cols + 32 zero pad = 65 * 64
#define NT    65     // K-tiles of 64
#define QMAXF 7.0f

using bf16_t = __hip_bfloat16;
typedef __attribute__((ext_vector_type(4))) float f32x4;
typedef __attribute__((ext_vector_type(8))) short bf16x8;

// ---------------------------------------------------------------------------
// async global->LDS 16B stage (LDS dest = wave-uniform base + lane*16)
// ---------------------------------------------------------------------------
__device__ __forceinline__ void stage16(const void* g, void* l) {
#if defined(__has_builtin) && __has_builtin(__builtin_amdgcn_global_load_lds)
  __builtin_amdgcn_global_load_lds(
      (const __attribute__((address_space(1))) unsigned int*)g,
      (__attribute__((address_space(3))) unsigned int*)l, 16, 0, 0);
#else
  *(uint4*)l = *(const uint4*)g;
#endif
}

// ---------------------------------------------------------------------------
// prep_w kernel: block-range dispatch.
//   blocks [0, 4096)    : quant_w -> Bp cols 0..4095, lora_up 4096..4127, pad
//   blocks [4096, 4112) : ldT     (lora_down [K][R] -> bf16 ldT [R][K])
// ---------------------------------------------------------------------------
__global__ __launch_bounds__(256) void prep_w_kernel(
    const float* __restrict__ w, const float* __restrict__ lora_up,
    const float* __restrict__ ld,
    bf16_t* __restrict__ Bp, bf16_t* __restrict__ ldT) {
  const int bid = blockIdx.x;
  const int tid = threadIdx.x;

  if (bid < N_DIM) {                       // ---- quant_w ----
    const int row = bid;
    const int k0  = tid * 16;
    const float* wr = w + (size_t)row * K_DIM + k0;

    float v[16];
#pragma unroll
    for (int i = 0; i < 4; ++i) {
      float4 wv = *(const float4*)(wr + i * 4);
      v[i*4+0] = wv.x; v[i*4+1] = wv.y; v[i*4+2] = wv.z; v[i*4+3] = wv.w;
    }
    float am = 0.f;
#pragma unroll
    for (int i = 0; i < 16; ++i) am = fmaxf(am, fabsf(v[i]));
    am = fmaxf(am, __shfl_xor(am, 1));
    am = fmaxf(am, __shfl_xor(am, 2));
    const float scale = fmaxf(am / QMAXF, 1e-8f);

    alignas(16) bf16_t o[16];
#pragma unroll
    for (int i = 0; i < 16; ++i) {
      float q = rintf(v[i] / scale);       // IEEE div + round-half-even = jnp
      q = fminf(fmaxf(q, -8.f), 7.f);
      o[i] = __float2bfloat16(q * scale);
    }
    bf16_t* dst = Bp + (size_t)row * KPAD + k0;
    ((uint4*)dst)[0] = ((uint4*)o)[0];
    ((uint4*)dst)[1] = ((uint4*)o)[1];
    if (tid < 32) {
      Bp[(size_t)row * KPAD + 4096 + tid] = __float2bfloat16(lora_up[row * R_DIM + tid]);
    } else if (tid < 64) {
      Bp[(size_t)row * KPAD + 4096 + tid] = __float2bfloat16(0.f);
    }

  } else {                                 // ---- ldT ----
    const int k = (bid - N_DIM) * 256 + tid;
    float v[R_DIM];
#pragma unroll
    for (int i = 0; i < R_DIM / 4; ++i) {
      float4 a = *(const float4*)(ld + (size_t)k * R_DIM + i * 4);
      v[i*4+0] = a.x; v[i*4+1] = a.y; v[i*4+2] = a.z; v[i*4+3] = a.w;
    }
#pragma unroll
    for (int r = 0; r < R_DIM; ++r)
      ldT[(size_t)r * K_DIM + k] = __float2bfloat16(v[r]);
  }
}

// ---------------------------------------------------------------------------
// fused_x kernel: SINGLE pass over x does BOTH
//   (a) smooth + per-group(64) int4 fake-quant -> Ap cols 0..4095 (+ zero pad)
//   (b) t = xs @ lora_down (both 16-col halves) -> Ap cols 4096..4127
// Block = 16 x-rows, 256 threads; wave w owns k-quarter [w*1024,(w+1)*1024).
// Measured (round 14): ~5.3 TB/s, near HBM ceiling.
// ---------------------------------------------------------------------------
__global__ __launch_bounds__(256) void fused_x_kernel(
    const float* __restrict__ x, const float* __restrict__ smooth,
    const bf16_t* __restrict__ ldT, bf16_t* __restrict__ Ap) {
  __shared__ float tpart[3][16][32];

  const int tid  = threadIdx.x;
  const int w    = tid >> 6;      // k-quarter 0..3
  const int lane = tid & 63;
  const int r    = lane & 15;     // x row within block
  const int kg   = lane >> 4;     // k-granule 0..3
  const int m0   = blockIdx.x * 16;
  const int mrow = m0 + r;

  const float*  xr  = x + (size_t)mrow * K_DIM;
  const bf16_t* br0 = ldT + (size_t)r * K_DIM;          // col tile 0: n = r
  const bf16_t* br1 = ldT + (size_t)(16 + r) * K_DIM;   // col tile 1: n = 16+r

  f32x4 acc0 = {0.f, 0.f, 0.f, 0.f};
  f32x4 acc1 = {0.f, 0.f, 0.f, 0.f};
  const int kbase = w * 1024;

  for (int s = 0; s < 32; s += 2) {
    const int ke = kbase + s * 32 + kg * 8;   // even step, this lane's 8 elems
    const int ko = ke + 32;                   // odd step

    float v[16];
    union { bf16_t h[8]; bf16x8 vv; } aue, auo;
    {
      float4 x0 = *(const float4*)(xr + ke);
      float4 x1 = *(const float4*)(xr + ke + 4);
      float4 s0 = *(const float4*)(smooth + ke);
      float4 s1 = *(const float4*)(smooth + ke + 4);
      v[0] = x0.x * s0.x; v[1] = x0.y * s0.y; v[2] = x0.z * s0.z; v[3] = x0.w * s0.w;
      v[4] = x1.x * s1.x; v[5] = x1.y * s1.y; v[6] = x1.z * s1.z; v[7] = x1.w * s1.w;
    }
    {
      float4 x0 = *(const float4*)(xr + ko);
      float4 x1 = *(const float4*)(xr + ko + 4);
      float4 s0 = *(const float4*)(smooth + ko);
      float4 s1 = *(const float4*)(smooth + ko + 4);
      v[8]  = x0.x * s0.x; v[9]  = x0.y * s0.y; v[10] = x0.z * s0.z; v[11] = x0.w * s0.w;
      v[12] = x1.x * s1.x; v[13] = x1.y * s1.y; v[14] = x1.z * s1.z; v[15] = x1.w * s1.w;
    }
#pragma unroll
    for (int i = 0; i < 8; ++i) {
      aue.h[i] = __float2bfloat16(v[i]);
      auo.h[i] = __float2bfloat16(v[8 + i]);
    }

    // lora MFMA (xs in bf16, both col tiles, both k-steps)
    acc0 = __builtin_amdgcn_mfma_f32_16x16x32_bf16(aue.vv, *(const bf16x8*)(br0 + ke), acc0, 0, 0, 0);
    acc1 = __builtin_amdgcn_mfma_f32_16x16x32_bf16(aue.vv, *(const bf16x8*)(br1 + ke), acc1, 0, 0, 0);
    acc0 = __builtin_amdgcn_mfma_f32_16x16x32_bf16(auo.vv, *(const bf16x8*)(br0 + ko), acc0, 0, 0, 0);
    acc1 = __builtin_amdgcn_mfma_f32_16x16x32_bf16(auo.vv, *(const bf16x8*)(br1 + ko), acc1, 0, 0, 0);

    // quantization of this group (64 k = lanes {r,r+16,r+32,r+48} x 16 elems)
    float am = 0.f;
#pragma unroll
    for (int i = 0; i < 16; ++i) am = fmaxf(am, fabsf(v[i]));
    am = fmaxf(am, __shfl_xor(am, 16));
    am = fmaxf(am, __shfl_xor(am, 32));
    const float scale = fmaxf(am / QMAXF, 1e-8f);

    alignas(16) bf16_t o[16];
#pragma unroll
    for (int i = 0; i < 16; ++i) {
      float q = rintf(v[i] / scale);       // IEEE div + round-half-even = jnp
      q = fminf(fmaxf(q, -8.f), 7.f);
      o[i] = __float2bfloat16(q * scale);
    }
    *(uint4*)(Ap + (size_t)mrow * KPAD + ke) = ((const uint4*)o)[0];
    *(uint4*)(Ap + (size_t)mrow * KPAD + ko) = ((const uint4*)o)[1];
  }

  // ---- cross-wave t reduction: C/D layout col=lane&15, row=(lane>>4)*4+q ----
  if (w != 0) {
#pragma unroll
    for (int q = 0; q < 4; ++q) {
      tpart[w - 1][kg * 4 + q][r]      = acc0[q];
      tpart[w - 1][kg * 4 + q][16 + r] = acc1[q];
    }
  }
  __syncthreads();
  if (w == 0) {
#pragma unroll
    for (int q = 0; q < 4; ++q) {
      const int orow = m0 + kg * 4 + q;
      float s0 = acc0[q], s1 = acc1[q];
#pragma unroll
      for (int j = 0; j < 3; ++j) {
        s0 += tpart[j][kg * 4 + q][r];
        s1 += tpart[j][kg * 4 + q][16 + r];
      }
      Ap[(size_t)orow * KPAD + 4096 + r]      = __float2bfloat16(s0);
      Ap[(size_t)orow * KPAD + 4096 + 16 + r] = __float2bfloat16(s1);
    }
    // zero pad cols 4128..4159
    alignas(16) bf16_t z[8] = {};
    *(uint4*)(Ap + (size_t)mrow * KPAD + 4128 + kg * 8) = *(const uint4*)z;
  }
}

// ---------------------------------------------------------------------------
// 256x256x64 8-phase GEMM, 4 barriers/ktile (round-16: bar3 removed).
// Full cross-wave WAR audit (stage victim -> last reader's draining lgkm0
// -> ordering barrier):
//   Ph2 STAGE_B(cur,0): victims LOAD_BN B-half0, drain Ph1-lgkm0 -> bar1 KEEP
//   Ph3 STAGE_B(cur,1): victims LOAD_BN B-half1, drain Ph1-lgkm0 -> bar1 ok
//   Ph4 STAGE_A(cur,0): q0 drains Ph1-lgkm0 (bar1); q1 drains Ph2-lgkm0
//                       -> bar2 KEEP
//   Ph1 STAGE_A(cur^1,1): q2 drains Ph3-lgkm0 (pre-bar4a); q3 drains
//                       Ph4-lgkm0 (post-bar4a) -> bar4b KEEP
//   bar4a: MANDATORY vmcnt(6) publication barrier (per-wave vmcnt,
//                       cross-wave LDS staging) KEEP
//   bar3: guards nothing -> REMOVED.
// vmcnt ring unchanged: at Ph4(u) queue = 14, retire 8 = all of ktile u+1.
// A quadrant-major LDS (lds_row = q*64 + wm*32 + r).  Swizzle: 16B granule
// ^= (row&7) on stage-source and ds_read (measured 0 conflicts).
// ---------------------------------------------------------------------------
__global__ __launch_bounds__(512, 2) void gemm_kernel(
    const bf16_t* __restrict__ A, const bf16_t* __restrict__ B,
    const float* __restrict__ bias, float* __restrict__ C) {
  extern __shared__ __align__(16) bf16_t lds[];   // 65536 elems = 128 KiB

  // XCD-aware swizzle: nwg = 512, divisible by 8
  const int wg  = blockIdx.x;
  const int swz = (wg & 7) * 64 + (wg >> 3);
  const int bn  = swz & 15;    // 0..15
  const int bm  = swz >> 4;    // 0..31

  const int tid  = threadIdx.x;
  const int lane = tid & 63;
  const int wid  = tid >> 6;     // 0..7
  const int wm   = wid >> 2;     // 0..1
  const int wn   = wid & 3;      // 0..3

  const int lr = lane & 15;      // frag row within 16
  const int lg = lane >> 4;      // k-granule subindex 0..3
  const int l7 = lane & 7;
  const int gk0 = ((0 + lg) ^ l7) * 8;   // swizzled elem offset, k-half 0
  const int gk1 = ((4 + lg) ^ l7) * 8;   // k-half 1

  // staging geometry
  const int sr   = tid >> 3;                 // 0..63
  const int sl   = tid & 7;                  // granule slot
  const int gcol = (sl ^ (sr & 7)) * 8;      // inverse-swizzled source col
  const bf16_t* Abase = A + (size_t)(bm * 256 + ((sr >> 5) & 1) * 128 + (sr & 31)) * KPAD + gcol;
  const bf16_t* Bbase = B + (size_t)(bn * 256 + sr) * KPAD + gcol;
  bf16_t* ldsb = lds;

#define STAGE_A(buf, h, kt) do {                                               \
    stage16(Abase + (size_t)((h) * 2 + 0) * 32 * KPAD + (kt) * 64,             \
            ldsb + (buf) * 32768 + (h) * 8192 + 0 * 4096 + tid * 8);           \
    stage16(Abase + (size_t)((h) * 2 + 1) * 32 * KPAD + (kt) * 64,             \
            ldsb + (buf) * 32768 + (h) * 8192 + 1 * 4096 + tid * 8);           \
  } while (0)
#define STAGE_B(buf, h, kt) do {                                               \
    stage16(Bbase + (size_t)((h) * 128 + 0) * KPAD + (kt) * 64,                \
            ldsb + (buf) * 32768 + 16384 + (h) * 8192 + 0 * 4096 + tid * 8);   \
    stage16(Bbase + (size_t)((h) * 128 + 64) * KPAD + (kt) * 64,               \
            ldsb + (buf) * 32768 + 16384 + (h) * 8192 + 1 * 4096 + tid * 8);   \
  } while (0)

  f32x4  acc[8][4] = {};
  bf16x8 aA[2][2];   // A-frag ping (quadrants 0,2)
  bf16x8 aB[2][2];   // A-frag pong (quadrants 1,3)
  bf16x8 bF[4][2];   // B-frags, one set, reloaded per ktile

#define LOAD_A(DST, q, cb) do {                                                \
    const bf16_t* pa_ = ldsb + (cb) * 32768 + ((q) * 64 + wm * 32 + lr) * 64;  \
    DST[0][0] = *(const bf16x8*)(pa_ + gk0);                                   \
    DST[0][1] = *(const bf16x8*)(pa_ + gk1);                                   \
    DST[1][0] = *(const bf16x8*)(pa_ + 1024 + gk0);                            \
    DST[1][1] = *(const bf16x8*)(pa_ + 1024 + gk1);                            \
  } while (0)
#define LOAD_BN(nbuf) do {                                                     \
    _Pragma("unroll")                                                          \
    for (int j = 0; j < 4; ++j) {                                              \
      const bf16_t* pb_ = ldsb + (nbuf) * 32768 + 16384 + (wn * 64 + j * 16 + lr) * 64; \
      bF[j][0] = *(const bf16x8*)(pb_ + gk0);                                  \
      bF[j][1] = *(const bf16x8*)(pb_ + gk1);                                  \
    }                                                                          \
  } while (0)
#define MFMA_Q(q, AARR) do {                                                   \
    _Pragma("unroll")                                                          \
    for (int i = 0; i < 2; ++i)                                                \
      _Pragma("unroll")                                                        \
      for (int j = 0; j < 4; ++j) {                                            \
        acc[(q)*2+i][j] = __builtin_amdgcn_mfma_f32_16x16x32_bf16(             \
            AARR[i][0], bF[j][0], acc[(q)*2+i][j], 0, 0, 0);                   \
        acc[(q)*2+i][j] = __builtin_amdgcn_mfma_f32_16x16x32_bf16(             \
            AARR[i][1], bF[j][1], acc[(q)*2+i][j], 0, 0, 0);                   \
      }                                                                        \
  } while (0)

#define KTILE(u, cur) do {                                                     \
    /* ---- Ph1: stage A2(u+1); drain P4-tail reads; MFMA q0 ---- */           \
    if ((u) + 1 < NT) STAGE_A((cur) ^ 1, 1, (u) + 1);                          \
    asm volatile("s_waitcnt lgkmcnt(0)" ::: "memory");                         \
    __builtin_amdgcn_sched_barrier(0);                                         \
    LOAD_A(aB, 1, cur);                                                        \
    __builtin_amdgcn_sched_barrier(0);                                         \
    __builtin_amdgcn_s_setprio(1);                                             \
    MFMA_Q(0, aA);                                                             \
    __builtin_amdgcn_s_setprio(0);                                             \
    __builtin_amdgcn_s_barrier();                     /* bar1 */               \
    /* ---- Ph2: stage B1(u+2); MFMA q1 ---- */                                \
    if ((u) + 2 < NT) STAGE_B(cur, 0, (u) + 2);                                \
    asm volatile("s_waitcnt lgkmcnt(0)" ::: "memory");                         \
    __builtin_amdgcn_sched_barrier(0);                                         \
    LOAD_A(aA, 2, cur);                                                        \
    __builtin_amdgcn_sched_barrier(0);                                         \
    __builtin_amdgcn_s_setprio(1);                                             \
    MFMA_Q(1, aB);                                                             \
    __builtin_amdgcn_s_setprio(0);                                             \
    __builtin_amdgcn_s_barrier();                     /* bar2 */               \
    /* ---- Ph3: stage B2(u+2); MFMA q2 (no close barrier: bar3 removed) */    \
    if ((u) + 2 < NT) STAGE_B(cur, 1, (u) + 2);                                \
    asm volatile("s_waitcnt lgkmcnt(0)" ::: "memory");                         \
    __builtin_amdgcn_sched_barrier(0);                                         \
    LOAD_A(aB, 3, cur);                                                        \
    __builtin_amdgcn_sched_barrier(0);                                         \
    __builtin_amdgcn_s_setprio(1);                                             \
    MFMA_Q(2, aA);                                                             \
    __builtin_amdgcn_s_setprio(0);                                             \
    /* ---- Ph4: stage A1(u+2); counted wait; MANDATORY barrier; MFMA q3 */    \
    if ((u) + 2 < NT) {                                                        \
      STAGE_A(cur, 0, (u) + 2);                                                \
      asm volatile("s_waitcnt vmcnt(6)" ::: "memory");                         \
    } else {                                                                   \
      asm volatile("s_waitcnt vmcnt(0)" ::: "memory");                         \
    }                                                                          \
    __builtin_amdgcn_s_barrier();                     /* bar4a (vmcnt) */      \
    asm volatile("s_waitcnt lgkmcnt(0)" ::: "memory");                         \
    __builtin_amdgcn_sched_barrier(0);                                         \
    if ((u) + 1 < NT) LOAD_A(aA, 0, (cur) ^ 1);                                \
    __builtin_amdgcn_sched_barrier(0);                                         \
    __builtin_amdgcn_s_setprio(1);                                             \
    MFMA_Q(3, aB);                                                             \
    __builtin_amdgcn_s_setprio(0);                                             \
    __builtin_amdgcn_sched_barrier(0);                                         \
    if ((u) + 1 < NT) LOAD_BN((cur) ^ 1);                                      \
    __builtin_amdgcn_s_barrier();                     /* bar4b */              \
  } while (0)

  // ---- prologue: stage ktile0 fully + ktile1's B1,B2,A1; wait ktile0;
  //      preload B(0) and A-q0(0) fragment registers ----
  STAGE_B(0, 0, 0); STAGE_B(0, 1, 0); STAGE_A(0, 0, 0); STAGE_A(0, 1, 0);
  STAGE_B(1, 0, 1); STAGE_B(1, 1, 1); STAGE_A(1, 0, 1);
  asm volatile("s_waitcnt vmcnt(6)" ::: "memory");
  __builtin_amdgcn_s_barrier();
  LOAD_BN(0);
  LOAD_A(aA, 0, 0);

  for (int base = 0; base < 64; base += 2) {
    KTILE(base,     0);
    KTILE(base + 1, 1);
  }
  KTILE(64, 0);

  // ---- epilogue: C/D layout col = lane&15, row = (lane>>4)*4 + e ----
  const int colb = bn * 256 + wn * 64 + lr;
  const int rowb = bm * 256 + wm * 128 + lg * 4;
#pragma unroll
  for (int j = 0; j < 4; ++j) {
    const int gc = colb + j * 16;
    const float bv = bias[gc];
#pragma unroll
    for (int q = 0; q < 4; ++q)
#pragma unroll
      for (int i = 0; i < 2; ++i) {
        const int gr = rowb + q * 32 + i * 16;
#pragma unroll
        for (int e = 0; e < 4; ++e)
          C[(size_t)(gr + e) * N_DIM + gc] = acc[q * 2 + i][j][e] + bv;
      }
  }
#undef STAGE_A
#undef STAGE_B
#undef LOAD_A
#undef LOAD_BN
#undef MFMA_Q
#undef KTILE
}

// ---------------------------------------------------------------------------
extern "C" void kernel_launch(void* const* d_in, const int* in_sizes, int n_in,
                              void* d_out, int out_size, void* d_ws, size_t ws_size,
                              hipStream_t stream) {
  const float* x         = (const float*)d_in[0];
  const float* w_res     = (const float*)d_in[1];
  const float* lora_down = (const float*)d_in[2];
  const float* lora_up   = (const float*)d_in[3];
  const float* smooth    = (const float*)d_in[4];
  const float* b         = (const float*)d_in[5];
  float* out = (float*)d_out;

  // workspace: Ap [M][KPAD] bf16 (68.2 MB), Bp [N][KPAD] bf16 (34.1 MB),
  // ldT [R][K] bf16 (256 KB)
  bf16_t* Ap  = (bf16_t*)d_ws;
  bf16_t* Bp  = Ap + (size_t)M_DIM * KPAD;
  bf16_t* ldT = Bp + (size_t)N_DIM * KPAD;

  // allow 128 KiB dynamic LDS (idempotent, host-side, capture-safe)
  hipFuncSetAttribute((const void*)gemm_kernel,
                      hipFuncAttributeMaxDynamicSharedMemorySize, 131072);

  prep_w_kernel<<<N_DIM + K_DIM / 256, 256, 0, stream>>>(
      w_res, lora_up, lora_down, Bp, ldT);
  fused_x_kernel<<<M_DIM / 16, 256, 0, stream>>>(x, smooth, ldT, Ap);
  gemm_kernel<<<(M_DIM / 256) * (N_DIM / 256), 512, 131072, stream>>>(Ap, Bp, b, out);
}